// Round 1
// baseline (854.439 us; speedup 1.0000x reference)
//
#include <hip/hip_runtime.h>
#include <hip/hip_bf16.h>
#include <stdint.h>

#define N_NODES   50000
#define N_EDGES   800000
#define D_MODEL   64
#define D_HIDDEN  256
#define N_GRAPHS  64
#define EPS_GN    1e-5f

typedef __attribute__((ext_vector_type(8))) short short8;   // 8 bf16 (4 VGPRs)
typedef __attribute__((ext_vector_type(4))) float f32x4;
typedef __attribute__((ext_vector_type(4))) float float4v;

static __device__ __forceinline__ short f2bf(float f) {
  union { float f; uint32_t u; } v; v.f = f;
  uint32_t r = (v.u + 0x7fffu + ((v.u >> 16) & 1u)) >> 16;   // RNE
  return (short)(uint16_t)r;
}

static __device__ __forceinline__ f32x4 mfma16(short8 a, short8 b, f32x4 c) {
  return __builtin_amdgcn_mfma_f32_16x16x32_bf16(a, b, c, 0, 0, 0);
}

// ---------------------------------------------------------------------------
// Weight prep: w [K][Nn] fp32 -> bf16 MFMA B-fragment layout [kt][nt][lane][8]
// frag element j of lane L = w[kt*32 + (L>>4)*8 + j][nt*16 + (L&15)]
// ---------------------------------------------------------------------------
__global__ void prep_w(const float* __restrict__ w, short* __restrict__ out,
                       int K, int Nn) {
  int t = blockIdx.x * 256 + threadIdx.x;
  int total = (K >> 5) * (Nn >> 4) * 64;
  if (t >= total) return;
  int lane = t & 63;
  int rest = t >> 6;
  int ntN = Nn >> 4;
  int nt = rest % ntN;
  int kt = rest / ntN;
  int n  = nt * 16 + (lane & 15);
  int k0 = kt * 32 + (lane >> 4) * 8;
  short* o = out + (size_t)t * 8;
#pragma unroll
  for (int j = 0; j < 8; ++j)
    o[j] = f2bf(w[(size_t)(k0 + j) * Nn + n]);
}

// ---------------------------------------------------------------------------
// Edge MLP: per block 64 edges. GEMM1 [64,160]x[160,256] -> silu ->
// GEMM2 [64,256]x[256,64] -> atomic scatter-add into agg[dst].
// ---------------------------------------------------------------------------
#define LDA_E 168   // 160 + 8 pad (bf16 elems), row stride 336 B (16B-aligned)
#define LDH   264   // 256 + 8 pad, row stride 528 B

__global__ __launch_bounds__(256, 2)
void edge_mlp(const float* __restrict__ h, const float* __restrict__ ea,
              const int* __restrict__ ei,
              const short* __restrict__ w1f, const float* __restrict__ b1,
              const short* __restrict__ w2f, const float* __restrict__ b2,
              float* __restrict__ agg) {
  __shared__ __align__(16) short sA[64 * LDA_E];
  __shared__ __align__(16) short sH[64 * LDH];

  const int tid  = threadIdx.x;
  const int lane = tid & 63;
  const int wave = tid >> 6;
  const int col  = lane & 15;
  const int quad = lane >> 4;
  const int eb   = blockIdx.x * 64;

  // ---- stage inputs: 64 edges x 160 fp32 (as 40 float4/edge) -> bf16 LDS
#pragma unroll
  for (int it = 0; it < 10; ++it) {
    int idx = it * 256 + tid;        // 0..2559
    int e   = idx / 40;
    int j   = idx - e * 40;
    int k   = j * 4;
    int ge  = eb + e;
    float4v v;
    if (k < 64) {
      int d = ei[N_EDGES + ge];
      v = *(const float4v*)(h + (size_t)d * D_MODEL + k);
    } else if (k < 128) {
      int s = ei[ge];
      v = *(const float4v*)(h + (size_t)s * D_MODEL + (k - 64));
    } else {
      v = *(const float4v*)(ea + (size_t)ge * 32 + (k - 128));
    }
    short* p = &sA[e * LDA_E + k];
    p[0] = f2bf(v.x); p[1] = f2bf(v.y); p[2] = f2bf(v.z); p[3] = f2bf(v.w);
  }
  __syncthreads();

  // ---- GEMM1: each wave handles N-slice of 64 cols (4 n-tiles), all 64 rows
  f32x4 acc[4][4];
#pragma unroll
  for (int mt = 0; mt < 4; ++mt)
#pragma unroll
    for (int nt = 0; nt < 4; ++nt)
      acc[mt][nt] = (f32x4){0.f, 0.f, 0.f, 0.f};

#pragma unroll
  for (int kt = 0; kt < 5; ++kt) {
    short8 af[4];
#pragma unroll
    for (int mt = 0; mt < 4; ++mt)
      af[mt] = *(const short8*)&sA[(mt * 16 + col) * LDA_E + kt * 32 + quad * 8];
#pragma unroll
    for (int nt = 0; nt < 4; ++nt) {
      const int ntg = wave * 4 + nt;
      short8 bf = *(const short8*)(w1f + (size_t)((kt * 16 + ntg) * 64 + lane) * 8);
#pragma unroll
      for (int mt = 0; mt < 4; ++mt)
        acc[mt][nt] = mfma16(af[mt], bf, acc[mt][nt]);
    }
  }

  // ---- bias + silu -> hidden LDS (bf16)
#pragma unroll
  for (int nt = 0; nt < 4; ++nt) {
    const int n = (wave * 4 + nt) * 16 + col;
    const float bias = b1[n];
#pragma unroll
    for (int mt = 0; mt < 4; ++mt) {
#pragma unroll
      for (int r = 0; r < 4; ++r) {
        const int row = mt * 16 + quad * 4 + r;
        float x = acc[mt][nt][r] + bias;
        float s = x / (1.0f + __expf(-x));
        sH[row * LDH + n] = f2bf(s);
      }
    }
  }
  __syncthreads();

  // ---- GEMM2: each wave handles M-slice of 16 rows, all 64 cols
  f32x4 acc2[4];
#pragma unroll
  for (int nt = 0; nt < 4; ++nt) acc2[nt] = (f32x4){0.f, 0.f, 0.f, 0.f};

#pragma unroll
  for (int kt = 0; kt < 8; ++kt) {
    short8 af = *(const short8*)&sH[(wave * 16 + col) * LDH + kt * 32 + quad * 8];
#pragma unroll
    for (int nt = 0; nt < 4; ++nt) {
      short8 bf = *(const short8*)(w2f + (size_t)((kt * 4 + nt) * 64 + lane) * 8);
      acc2[nt] = mfma16(af, bf, acc2[nt]);
    }
  }

  // ---- bias + atomic scatter into agg[dst]
  int dst_r[4];
#pragma unroll
  for (int r = 0; r < 4; ++r)
    dst_r[r] = ei[N_EDGES + eb + wave * 16 + quad * 4 + r];
#pragma unroll
  for (int nt = 0; nt < 4; ++nt) {
    const int n = nt * 16 + col;
    const float bias = b2[n];
#pragma unroll
    for (int r = 0; r < 4; ++r)
      atomicAdd(agg + (size_t)dst_r[r] * D_MODEL + n, acc2[nt][r] + bias);
  }
}

// ---------------------------------------------------------------------------
// Node MLP: per block 64 nodes. in = [h, agg] (K=128). h_new = h + dh -> d_out
// ---------------------------------------------------------------------------
#define LDA_N 136   // 128 + 8 pad, row stride 272 B

__global__ __launch_bounds__(256, 2)
void node_mlp(const float* __restrict__ h, const float* __restrict__ agg,
              const short* __restrict__ w1f, const float* __restrict__ b1,
              const short* __restrict__ w2f, const float* __restrict__ b2,
              float* __restrict__ hnew) {
  __shared__ __align__(16) short sA[64 * LDA_N];
  __shared__ __align__(16) short sH[64 * LDH];

  const int tid  = threadIdx.x;
  const int lane = tid & 63;
  const int wave = tid >> 6;
  const int col  = lane & 15;
  const int quad = lane >> 4;
  const int nb   = blockIdx.x * 64;

  // ---- stage: 64 nodes x 128 fp32 (32 float4/node)
#pragma unroll
  for (int it = 0; it < 8; ++it) {
    int idx = it * 256 + tid;   // 0..2047
    int i   = idx >> 5;
    int j   = idx & 31;
    int k   = j * 4;
    int gi  = nb + i;
    if (gi >= N_NODES) gi = N_NODES - 1;   // clamp; OOB rows never stored
    float4v v = (k < 64) ? *(const float4v*)(h + (size_t)gi * D_MODEL + k)
                         : *(const float4v*)(agg + (size_t)gi * D_MODEL + (k - 64));
    short* p = &sA[i * LDA_N + k];
    p[0] = f2bf(v.x); p[1] = f2bf(v.y); p[2] = f2bf(v.z); p[3] = f2bf(v.w);
  }
  __syncthreads();

  // ---- GEMM1: K=128
  f32x4 acc[4][4];
#pragma unroll
  for (int mt = 0; mt < 4; ++mt)
#pragma unroll
    for (int nt = 0; nt < 4; ++nt)
      acc[mt][nt] = (f32x4){0.f, 0.f, 0.f, 0.f};

#pragma unroll
  for (int kt = 0; kt < 4; ++kt) {
    short8 af[4];
#pragma unroll
    for (int mt = 0; mt < 4; ++mt)
      af[mt] = *(const short8*)&sA[(mt * 16 + col) * LDA_N + kt * 32 + quad * 8];
#pragma unroll
    for (int nt = 0; nt < 4; ++nt) {
      const int ntg = wave * 4 + nt;
      short8 bf = *(const short8*)(w1f + (size_t)((kt * 16 + ntg) * 64 + lane) * 8);
#pragma unroll
      for (int mt = 0; mt < 4; ++mt)
        acc[mt][nt] = mfma16(af[mt], bf, acc[mt][nt]);
    }
  }

#pragma unroll
  for (int nt = 0; nt < 4; ++nt) {
    const int n = (wave * 4 + nt) * 16 + col;
    const float bias = b1[n];
#pragma unroll
    for (int mt = 0; mt < 4; ++mt) {
#pragma unroll
      for (int r = 0; r < 4; ++r) {
        const int row = mt * 16 + quad * 4 + r;
        float x = acc[mt][nt][r] + bias;
        float s = x / (1.0f + __expf(-x));
        sH[row * LDH + n] = f2bf(s);
      }
    }
  }
  __syncthreads();

  // ---- GEMM2: K=256
  f32x4 acc2[4];
#pragma unroll
  for (int nt = 0; nt < 4; ++nt) acc2[nt] = (f32x4){0.f, 0.f, 0.f, 0.f};

#pragma unroll
  for (int kt = 0; kt < 8; ++kt) {
    short8 af = *(const short8*)&sH[(wave * 16 + col) * LDH + kt * 32 + quad * 8];
#pragma unroll
    for (int nt = 0; nt < 4; ++nt) {
      short8 bf = *(const short8*)(w2f + (size_t)((kt * 4 + nt) * 64 + lane) * 8);
      acc2[nt] = mfma16(af, bf, acc2[nt]);
    }
  }

  // ---- h_new = h + dh
#pragma unroll
  for (int r = 0; r < 4; ++r) {
    const int row = wave * 16 + quad * 4 + r;
    const int gi = nb + row;
    if (gi < N_NODES) {
#pragma unroll
      for (int nt = 0; nt < 4; ++nt) {
        const int n = nt * 16 + col;
        hnew[(size_t)gi * D_MODEL + n] =
            h[(size_t)gi * D_MODEL + n] + acc2[nt][r] + b2[n];
      }
    }
  }
}

// ---------------------------------------------------------------------------
// GraphNorm (batch is sorted). Chunked segmented partial sums + few atomics.
// ---------------------------------------------------------------------------
#define GN_CHUNK 256

__global__ __launch_bounds__(64)
void gn_stats1(const float* __restrict__ x, const int* __restrict__ batch,
               float* __restrict__ sums, float* __restrict__ cnt) {
  const int f = threadIdx.x;
  const int base = blockIdx.x * GN_CHUNK;
  const int end = (base + GN_CHUNK < N_NODES) ? base + GN_CHUNK : N_NODES;
  float s = 0.f;
  int cur = batch[base], c0 = base;
  for (int i = base; i < end; ++i) {
    int g = batch[i];
    if (g != cur) {
      atomicAdd(&sums[cur * D_MODEL + f], s);
      if (f == 0) atomicAdd(&cnt[cur], (float)(i - c0));
      s = 0.f; cur = g; c0 = i;
    }
    s += x[(size_t)i * D_MODEL + f];
  }
  atomicAdd(&sums[cur * D_MODEL + f], s);
  if (f == 0) atomicAdd(&cnt[cur], (float)(end - c0));
}

__global__ __launch_bounds__(64)
void gn_stats2(const float* __restrict__ x, const int* __restrict__ batch,
               const float* __restrict__ sums, const float* __restrict__ cnt,
               const float* __restrict__ alpha, float* __restrict__ varsums) {
  const int f = threadIdx.x;
  const int base = blockIdx.x * GN_CHUNK;
  const int end = (base + GN_CHUNK < N_NODES) ? base + GN_CHUNK : N_NODES;
  const float a = alpha[f];
  int cur = batch[base];
  float c = fmaxf(cnt[cur], 1.f);
  float am = a * sums[cur * D_MODEL + f] / c;
  float s = 0.f;
  for (int i = base; i < end; ++i) {
    int g = batch[i];
    if (g != cur) {
      atomicAdd(&varsums[cur * D_MODEL + f], s);
      s = 0.f; cur = g;
      c = fmaxf(cnt[cur], 1.f);
      am = a * sums[cur * D_MODEL + f] / c;
    }
    float d = x[(size_t)i * D_MODEL + f] - am;
    s += d * d;
  }
  atomicAdd(&varsums[cur * D_MODEL + f], s);
}

__global__ __launch_bounds__(256)
void gn_norm(float* __restrict__ x, const int* __restrict__ batch,
             const float* __restrict__ sums, const float* __restrict__ varsums,
             const float* __restrict__ cnt, const float* __restrict__ alpha,
             const float* __restrict__ weight, const float* __restrict__ bias) {
  int idx = blockIdx.x * 256 + threadIdx.x;
  if (idx >= N_NODES * D_MODEL) return;
  int i = idx >> 6, f = idx & 63;
  int g = batch[i];
  float c = fmaxf(cnt[g], 1.f);
  float mean = sums[g * D_MODEL + f] / c;
  float var  = varsums[g * D_MODEL + f] / c;
  float hc = x[idx] - alpha[f] * mean;
  x[idx] = weight[f] * hc * rsqrtf(var + EPS_GN) + bias[f];
}

// ---------------------------------------------------------------------------
extern "C" void kernel_launch(void* const* d_in, const int* in_sizes, int n_in,
                              void* d_out, int out_size, void* d_ws, size_t ws_size,
                              hipStream_t stream) {
  const float* h     = (const float*)d_in[0];
  const float* ea    = (const float*)d_in[1];
  const int*   ei    = (const int*)d_in[2];   // [2][E], row0=src, row1=dst
  const int*   batch = (const int*)d_in[3];
  const float* mw1   = (const float*)d_in[4];
  const float* mb1   = (const float*)d_in[5];
  const float* mw2   = (const float*)d_in[6];
  const float* mb2   = (const float*)d_in[7];
  const float* uw1   = (const float*)d_in[8];
  const float* ub1   = (const float*)d_in[9];
  const float* uw2   = (const float*)d_in[10];
  const float* ub2   = (const float*)d_in[11];
  const float* gw    = (const float*)d_in[12];
  const float* gb    = (const float*)d_in[13];
  const float* ga    = (const float*)d_in[14];

  char* ws = (char*)d_ws;
  float* agg   = (float*)(ws + 0);             // 12,800,000 B
  short* w1f   = (short*)(ws + 12800000);      //     81,920 B (160x256 bf16 frags)
  short* w2f   = (short*)(ws + 12881920);      //     32,768 B (256x64)
  short* u1f   = (short*)(ws + 12914688);      //     65,536 B (128x256)
  short* u2f   = (short*)(ws + 12980224);      //     32,768 B (256x64)
  float* sums  = (float*)(ws + 13012992);      //     16,384 B
  float* vars  = (float*)(ws + 13029376);      //     16,384 B
  float* cnt   = (float*)(ws + 13045760);      //        256 B

  hipMemsetAsync(agg, 0, 12800000, stream);
  hipMemsetAsync(ws + 13012992, 0, 33024, stream);

  prep_w<<<20, 256, 0, stream>>>(mw1, w1f, 160, 256);
  prep_w<<<8,  256, 0, stream>>>(mw2, w2f, 256, 64);
  prep_w<<<16, 256, 0, stream>>>(uw1, u1f, 128, 256);
  prep_w<<<8,  256, 0, stream>>>(uw2, u2f, 256, 64);

  edge_mlp<<<N_EDGES / 64, 256, 0, stream>>>(h, ea, ei, w1f, mb1, w2f, mb2, agg);

  node_mlp<<<(N_NODES + 63) / 64, 256, 0, stream>>>(h, agg, u1f, ub1, u2f, ub2,
                                                    (float*)d_out);

  int gn_blocks = (N_NODES + GN_CHUNK - 1) / GN_CHUNK;
  gn_stats1<<<gn_blocks, 64, 0, stream>>>((const float*)d_out, batch, sums, cnt);
  gn_stats2<<<gn_blocks, 64, 0, stream>>>((const float*)d_out, batch, sums, cnt, ga, vars);
  gn_norm<<<(N_NODES * D_MODEL + 255) / 256, 256, 0, stream>>>(
      (float*)d_out, batch, sums, vars, cnt, ga, gw, gb);
}

// Round 2
// 798.333 us; speedup vs baseline: 1.0703x; 1.0703x over previous
//
#include <hip/hip_runtime.h>
#include <hip/hip_bf16.h>
#include <stdint.h>

#define N_NODES   50000
#define N_EDGES   800000
#define D_MODEL   64
#define D_HIDDEN  256
#define N_GRAPHS  64
#define EPS_GN    1e-5f

typedef __attribute__((ext_vector_type(8))) short short8;   // 8 bf16 (4 VGPRs)
typedef __attribute__((ext_vector_type(4))) float f32x4;
typedef __attribute__((ext_vector_type(4))) float float4v;

static __device__ __forceinline__ short f2bf(float f) {
  union { float f; uint32_t u; } v; v.f = f;
  uint32_t r = (v.u + 0x7fffu + ((v.u >> 16) & 1u)) >> 16;   // RNE
  return (short)(uint16_t)r;
}

static __device__ __forceinline__ f32x4 mfma16(short8 a, short8 b, f32x4 c) {
  return __builtin_amdgcn_mfma_f32_16x16x32_bf16(a, b, c, 0, 0, 0);
}

// ---------------------------------------------------------------------------
// Weight prep (all 4 mats in one launch): w [K][Nn] fp32 -> bf16 MFMA
// B-fragment layout [kt][nt][lane][8];
// frag elem j of lane L = w[kt*32 + (L>>4)*8 + j][nt*16 + (L&15)]
// ---------------------------------------------------------------------------
__global__ void prep_all(const float* __restrict__ mw1, const float* __restrict__ mw2,
                         const float* __restrict__ uw1, const float* __restrict__ uw2,
                         short* __restrict__ w1f, short* __restrict__ w2f,
                         short* __restrict__ u1f, short* __restrict__ u2f) {
  int b = blockIdx.x;
  const float* w; short* out; int K, Nn, t;
  if (b < 20)      { w = mw1; out = w1f; K = 160; Nn = 256; t = b * 256 + threadIdx.x; }
  else if (b < 28) { w = mw2; out = w2f; K = 256; Nn = 64;  t = (b - 20) * 256 + threadIdx.x; }
  else if (b < 44) { w = uw1; out = u1f; K = 128; Nn = 256; t = (b - 28) * 256 + threadIdx.x; }
  else             { w = uw2; out = u2f; K = 256; Nn = 64;  t = (b - 44) * 256 + threadIdx.x; }
  int total = (K >> 5) * (Nn >> 4) * 64;
  if (t >= total) return;
  int lane = t & 63;
  int rest = t >> 6;
  int ntN = Nn >> 4;
  int nt = rest % ntN;
  int kt = rest / ntN;
  int n  = nt * 16 + (lane & 15);
  int k0 = kt * 32 + (lane >> 4) * 8;
  short* o = out + (size_t)t * 8;
#pragma unroll
  for (int j = 0; j < 8; ++j)
    o[j] = f2bf(w[(size_t)(k0 + j) * Nn + n]);
}

// ---------------------------------------------------------------------------
// Edge MLP — barrier-free: each WAVE owns 16 edges end-to-end.
// Per-wave LDS slab reused for input tile (16 x LDA_E) then hidden (16 x LDH).
// Same-wave ds_write -> ds_read ordering is guaranteed by lgkmcnt (no
// __syncthreads anywhere), so waves free-run; 33.8 KB LDS -> 4 blocks/CU.
// ---------------------------------------------------------------------------
#define LDA_E 168   // 160 + 8 pad shorts; row = 336 B (16B aligned)
#define LDH   264   // 256 + 8 pad shorts; row = 528 B (16B aligned)
#define SLAB  (16 * LDH)   // 4224 shorts >= 16*LDA_E

__global__ __launch_bounds__(256, 4)
void edge_mlp(const float* __restrict__ h, const float* __restrict__ ea,
              const int* __restrict__ ei,
              const short* __restrict__ w1f, const float* __restrict__ b1,
              const short* __restrict__ w2f, const float* __restrict__ b2,
              float* __restrict__ agg) {
  __shared__ __align__(16) short slab[4 * SLAB];

  const int tid  = threadIdx.x;
  const int lane = tid & 63;
  const int wave = tid >> 6;
  const int col  = lane & 15;
  const int quad = lane >> 4;
  const int eb   = blockIdx.x * 64 + wave * 16;   // this wave's 16 edges
  short* sA = slab + wave * SLAB;                 // [16][LDA_E]
  short* sH = slab + wave * SLAB;                 // [16][LDH] (reused)

  // ---- stage: 16 edges x 160 fp32 (40 float4/edge) -> bf16 LDS
#pragma unroll
  for (int it = 0; it < 10; ++it) {
    int idx = it * 64 + lane;       // 0..639
    int e   = idx / 40;
    int j   = idx - e * 40;
    int k   = j * 4;
    int ge  = eb + e;
    float4v v;
    if (k < 64) {
      int d = ei[N_EDGES + ge];
      v = *(const float4v*)(h + (size_t)d * D_MODEL + k);
    } else if (k < 128) {
      int s = ei[ge];
      v = *(const float4v*)(h + (size_t)s * D_MODEL + (k - 64));
    } else {
      v = *(const float4v*)(ea + (size_t)ge * 32 + (k - 128));
    }
    short* p = &sA[e * LDA_E + k];
    p[0] = f2bf(v.x); p[1] = f2bf(v.y); p[2] = f2bf(v.z); p[3] = f2bf(v.w);
  }

  // ---- GEMM1: [16,160] x [160,256], wave-private. acc over 16 n-tiles.
  f32x4 acc[16];
#pragma unroll
  for (int nt = 0; nt < 16; ++nt) acc[nt] = (f32x4){0.f, 0.f, 0.f, 0.f};

#pragma unroll
  for (int kt = 0; kt < 5; ++kt) {
    short8 af = *(const short8*)&sA[col * LDA_E + kt * 32 + quad * 8];
#pragma unroll
    for (int nt = 0; nt < 16; ++nt) {
      short8 bf = *(const short8*)(w1f + (size_t)((kt * 16 + nt) * 64 + lane) * 8);
      acc[nt] = mfma16(af, bf, acc[nt]);
    }
  }

  // ---- bias + silu -> hidden (overwrites own slab; wave-local ordering)
#pragma unroll
  for (int nt = 0; nt < 16; ++nt) {
    const int n = nt * 16 + col;
    const float bias = b1[n];
#pragma unroll
    for (int r = 0; r < 4; ++r) {
      const int row = quad * 4 + r;
      float x = acc[nt][r] + bias;
      float s = x / (1.0f + __expf(-x));
      sH[row * LDH + n] = f2bf(s);
    }
  }

  // ---- GEMM2: [16,256] x [256,64]
  f32x4 acc2[4];
#pragma unroll
  for (int nt = 0; nt < 4; ++nt) acc2[nt] = (f32x4){0.f, 0.f, 0.f, 0.f};

#pragma unroll
  for (int kt = 0; kt < 8; ++kt) {
    short8 af = *(const short8*)&sH[col * LDH + kt * 32 + quad * 8];
#pragma unroll
    for (int nt = 0; nt < 4; ++nt) {
      short8 bf = *(const short8*)(w2f + (size_t)((kt * 4 + nt) * 64 + lane) * 8);
      acc2[nt] = mfma16(af, bf, acc2[nt]);
    }
  }

  // ---- bias + atomic scatter into agg[dst]
  int dst_r[4];
#pragma unroll
  for (int r = 0; r < 4; ++r)
    dst_r[r] = ei[N_EDGES + eb + quad * 4 + r];
#pragma unroll
  for (int nt = 0; nt < 4; ++nt) {
    const int n = nt * 16 + col;
    const float bias = b2[n];
#pragma unroll
    for (int r = 0; r < 4; ++r)
      atomicAdd(agg + (size_t)dst_r[r] * D_MODEL + n, acc2[nt][r] + bias);
  }
}

// ---------------------------------------------------------------------------
// Node MLP — same barrier-free wave-private structure. 16 nodes per wave.
// ---------------------------------------------------------------------------
#define LDA_N 136   // 128 + 8 pad shorts; row = 272 B

__global__ __launch_bounds__(256, 4)
void node_mlp(const float* __restrict__ h, const float* __restrict__ agg,
              const short* __restrict__ w1f, const float* __restrict__ b1,
              const short* __restrict__ w2f, const float* __restrict__ b2,
              float* __restrict__ hnew) {
  __shared__ __align__(16) short slab[4 * SLAB];

  const int tid  = threadIdx.x;
  const int lane = tid & 63;
  const int wave = tid >> 6;
  const int col  = lane & 15;
  const int quad = lane >> 4;
  const int nb   = blockIdx.x * 64 + wave * 16;
  short* sA = slab + wave * SLAB;   // [16][LDA_N]
  short* sH = slab + wave * SLAB;   // [16][LDH]

  // ---- stage: 16 nodes x 128 fp32 (32 float4/node)
#pragma unroll
  for (int it = 0; it < 8; ++it) {
    int idx = it * 64 + lane;     // 0..511
    int i   = idx >> 5;
    int j   = idx & 31;
    int k   = j * 4;
    int gi  = nb + i;
    if (gi >= N_NODES) gi = N_NODES - 1;   // clamp; OOB rows never stored
    float4v v = (k < 64) ? *(const float4v*)(h + (size_t)gi * D_MODEL + k)
                         : *(const float4v*)(agg + (size_t)gi * D_MODEL + (k - 64));
    short* p = &sA[i * LDA_N + k];
    p[0] = f2bf(v.x); p[1] = f2bf(v.y); p[2] = f2bf(v.z); p[3] = f2bf(v.w);
  }

  // ---- GEMM1: K=128
  f32x4 acc[16];
#pragma unroll
  for (int nt = 0; nt < 16; ++nt) acc[nt] = (f32x4){0.f, 0.f, 0.f, 0.f};

#pragma unroll
  for (int kt = 0; kt < 4; ++kt) {
    short8 af = *(const short8*)&sA[col * LDA_N + kt * 32 + quad * 8];
#pragma unroll
    for (int nt = 0; nt < 16; ++nt) {
      short8 bf = *(const short8*)(w1f + (size_t)((kt * 16 + nt) * 64 + lane) * 8);
      acc[nt] = mfma16(af, bf, acc[nt]);
    }
  }

#pragma unroll
  for (int nt = 0; nt < 16; ++nt) {
    const int n = nt * 16 + col;
    const float bias = b1[n];
#pragma unroll
    for (int r = 0; r < 4; ++r) {
      const int row = quad * 4 + r;
      float x = acc[nt][r] + bias;
      float s = x / (1.0f + __expf(-x));
      sH[row * LDH + n] = f2bf(s);
    }
  }

  // ---- GEMM2: K=256
  f32x4 acc2[4];
#pragma unroll
  for (int nt = 0; nt < 4; ++nt) acc2[nt] = (f32x4){0.f, 0.f, 0.f, 0.f};

#pragma unroll
  for (int kt = 0; kt < 8; ++kt) {
    short8 af = *(const short8*)&sH[col * LDH + kt * 32 + quad * 8];
#pragma unroll
    for (int nt = 0; nt < 4; ++nt) {
      short8 bf = *(const short8*)(w2f + (size_t)((kt * 4 + nt) * 64 + lane) * 8);
      acc2[nt] = mfma16(af, bf, acc2[nt]);
    }
  }

  // ---- h_new = h + dh
#pragma unroll
  for (int r = 0; r < 4; ++r) {
    const int gi = nb + quad * 4 + r;
    if (gi < N_NODES) {
#pragma unroll
      for (int nt = 0; nt < 4; ++nt) {
        const int n = nt * 16 + col;
        hnew[(size_t)gi * D_MODEL + n] =
            h[(size_t)gi * D_MODEL + n] + acc2[nt][r] + b2[n];
      }
    }
  }
}

// ---------------------------------------------------------------------------
// GraphNorm — single-pass stats (S1, S2, count), batch is sorted.
// var(x - a*m) = S2/c - 2*a*m*(S1/c) + a^2*m^2,  m = S1/c.
// ---------------------------------------------------------------------------
#define GN_CHUNK 64

__global__ __launch_bounds__(64)
void gn_stats(const float* __restrict__ x, const int* __restrict__ batch,
              float* __restrict__ s1, float* __restrict__ s2,
              float* __restrict__ cnt) {
  const int f = threadIdx.x;
  const int base = blockIdx.x * GN_CHUNK;
  const int end = (base + GN_CHUNK < N_NODES) ? base + GN_CHUNK : N_NODES;
  float a1 = 0.f, a2 = 0.f;
  int cur = batch[base], c0 = base;
  for (int i = base; i < end; ++i) {
    int g = batch[i];
    if (g != cur) {
      atomicAdd(&s1[cur * D_MODEL + f], a1);
      atomicAdd(&s2[cur * D_MODEL + f], a2);
      if (f == 0) atomicAdd(&cnt[cur], (float)(i - c0));
      a1 = 0.f; a2 = 0.f; cur = g; c0 = i;
    }
    float v = x[(size_t)i * D_MODEL + f];
    a1 += v; a2 += v * v;
  }
  atomicAdd(&s1[cur * D_MODEL + f], a1);
  atomicAdd(&s2[cur * D_MODEL + f], a2);
  if (f == 0) atomicAdd(&cnt[cur], (float)(end - c0));
}

__global__ __launch_bounds__(256)
void gn_norm(float* __restrict__ x, const int* __restrict__ batch,
             const float* __restrict__ s1, const float* __restrict__ s2,
             const float* __restrict__ cnt, const float* __restrict__ alpha,
             const float* __restrict__ weight, const float* __restrict__ bias) {
  int idx = blockIdx.x * 256 + threadIdx.x;
  if (idx >= N_NODES * D_MODEL) return;
  int i = idx >> 6, f = idx & 63;
  int g = batch[i];
  float c = fmaxf(cnt[g], 1.f);
  float m  = s1[g * D_MODEL + f] / c;
  float ex2 = s2[g * D_MODEL + f] / c;
  float a = alpha[f];
  float var = ex2 - 2.f * a * m * m + a * a * m * m;
  float hc = x[idx] - a * m;
  x[idx] = weight[f] * hc * rsqrtf(var + EPS_GN) + bias[f];
}

// ---------------------------------------------------------------------------
extern "C" void kernel_launch(void* const* d_in, const int* in_sizes, int n_in,
                              void* d_out, int out_size, void* d_ws, size_t ws_size,
                              hipStream_t stream) {
  const float* h     = (const float*)d_in[0];
  const float* ea    = (const float*)d_in[1];
  const int*   ei    = (const int*)d_in[2];   // [2][E], row0=src, row1=dst
  const int*   batch = (const int*)d_in[3];
  const float* mw1   = (const float*)d_in[4];
  const float* mb1   = (const float*)d_in[5];
  const float* mw2   = (const float*)d_in[6];
  const float* mb2   = (const float*)d_in[7];
  const float* uw1   = (const float*)d_in[8];
  const float* ub1   = (const float*)d_in[9];
  const float* uw2   = (const float*)d_in[10];
  const float* ub2   = (const float*)d_in[11];
  const float* gw    = (const float*)d_in[12];
  const float* gb    = (const float*)d_in[13];
  const float* ga    = (const float*)d_in[14];

  char* ws = (char*)d_ws;
  float* agg  = (float*)(ws + 0);             // 12,800,000 B
  short* w1f  = (short*)(ws + 12800000);      //     81,920 B
  short* w2f  = (short*)(ws + 12881920);      //     32,768 B
  short* u1f  = (short*)(ws + 12914688);      //     65,536 B
  short* u2f  = (short*)(ws + 12980224);      //     32,768 B
  float* s1   = (float*)(ws + 13012992);      //     16,384 B
  float* s2   = (float*)(ws + 13029376);      //     16,384 B
  float* cnt  = (float*)(ws + 13045760);      //        256 B

  hipMemsetAsync(agg, 0, 12800000, stream);
  hipMemsetAsync(ws + 13012992, 0, 33024, stream);

  prep_all<<<52, 256, 0, stream>>>(mw1, mw2, uw1, uw2, w1f, w2f, u1f, u2f);

  edge_mlp<<<N_EDGES / 64, 256, 0, stream>>>(h, ea, ei, w1f, mb1, w2f, mb2, agg);

  node_mlp<<<(N_NODES + 63) / 64, 256, 0, stream>>>(h, agg, u1f, ub1, u2f, ub2,
                                                    (float*)d_out);

  int gn_blocks = (N_NODES + GN_CHUNK - 1) / GN_CHUNK;
  gn_stats<<<gn_blocks, 64, 0, stream>>>((const float*)d_out, batch, s1, s2, cnt);
  gn_norm<<<(N_NODES * D_MODEL + 255) / 256, 256, 0, stream>>>(
      (float*)d_out, batch, s1, s2, cnt, ga, gw, gb);
}

// Round 3
// 794.725 us; speedup vs baseline: 1.0751x; 1.0045x over previous
//
#include <hip/hip_runtime.h>
#include <hip/hip_bf16.h>
#include <stdint.h>

#define N_NODES   50000
#define N_EDGES   800000
#define D_MODEL   64
#define D_HIDDEN  256
#define N_GRAPHS  64
#define EPS_GN    1e-5f

#define NBINS_PAD 50176            // 196 * 256, zero-padded histogram
#define NB_SCAN   196

typedef __attribute__((ext_vector_type(8))) short short8;   // 8 bf16 (4 VGPRs)
typedef __attribute__((ext_vector_type(4))) float f32x4;
typedef __attribute__((ext_vector_type(4))) float float4v;

static __device__ __forceinline__ short f2bf(float f) {
  union { float f; uint32_t u; } v; v.f = f;
  uint32_t r = (v.u + 0x7fffu + ((v.u >> 16) & 1u)) >> 16;   // RNE
  return (short)(uint16_t)r;
}

static __device__ __forceinline__ f32x4 mfma16(short8 a, short8 b, f32x4 c) {
  return __builtin_amdgcn_mfma_f32_16x16x32_bf16(a, b, c, 0, 0, 0);
}

// ---------------------------------------------------------------------------
// Weight prep (all 4 mats): w [K][Nn] fp32 -> bf16 MFMA B-fragment layout
// [kt][nt][lane][8]; frag elem j of lane L = w[kt*32+(L>>4)*8+j][nt*16+(L&15)]
// ---------------------------------------------------------------------------
__global__ void prep_all(const float* __restrict__ mw1, const float* __restrict__ mw2,
                         const float* __restrict__ uw1, const float* __restrict__ uw2,
                         short* __restrict__ w1f, short* __restrict__ w2f,
                         short* __restrict__ u1f, short* __restrict__ u2f) {
  int b = blockIdx.x;
  const float* w; short* out; int K, Nn, t;
  if (b < 20)      { w = mw1; out = w1f; K = 160; Nn = 256; t = b * 256 + threadIdx.x; }
  else if (b < 28) { w = mw2; out = w2f; K = 256; Nn = 64;  t = (b - 20) * 256 + threadIdx.x; }
  else if (b < 44) { w = uw1; out = u1f; K = 128; Nn = 256; t = (b - 28) * 256 + threadIdx.x; }
  else             { w = uw2; out = u2f; K = 256; Nn = 64;  t = (b - 44) * 256 + threadIdx.x; }
  int total = (K >> 5) * (Nn >> 4) * 64;
  if (t >= total) return;
  int lane = t & 63;
  int rest = t >> 6;
  int ntN = Nn >> 4;
  int nt = rest % ntN;
  int kt = rest / ntN;
  int n  = nt * 16 + (lane & 15);
  int k0 = kt * 32 + (lane >> 4) * 8;
  short* o = out + (size_t)t * 8;
#pragma unroll
  for (int j = 0; j < 8; ++j)
    o[j] = f2bf(w[(size_t)(k0 + j) * Nn + n]);
}

// ---------------------------------------------------------------------------
// Counting sort of edges by dst: hist -> 2-level exclusive scan -> scatter.
// ---------------------------------------------------------------------------
__global__ __launch_bounds__(256)
void hist_k(const int* __restrict__ ei, int* __restrict__ hist) {
  int e = blockIdx.x * 256 + threadIdx.x;
  if (e >= N_EDGES) return;
  atomicAdd(&hist[ei[N_EDGES + e]], 1);
}

__global__ __launch_bounds__(256)
void scan1(const int* __restrict__ hist, int* __restrict__ offs,
           int* __restrict__ bsums) {
  __shared__ int tmp[256];
  int i = blockIdx.x * 256 + threadIdx.x;
  int v = hist[i];
  tmp[threadIdx.x] = v;
  __syncthreads();
#pragma unroll
  for (int d = 1; d < 256; d <<= 1) {
    int t = (threadIdx.x >= d) ? tmp[threadIdx.x - d] : 0;
    __syncthreads();
    tmp[threadIdx.x] += t;
    __syncthreads();
  }
  offs[i] = tmp[threadIdx.x] - v;                 // exclusive within block
  if (threadIdx.x == 255) bsums[blockIdx.x] = tmp[255];
}

__global__ __launch_bounds__(256)
void scan2(const int* __restrict__ bsums, int* __restrict__ bpre) {
  __shared__ int tmp[256];
  int v = (threadIdx.x < NB_SCAN) ? bsums[threadIdx.x] : 0;
  tmp[threadIdx.x] = v;
  __syncthreads();
#pragma unroll
  for (int d = 1; d < 256; d <<= 1) {
    int t = (threadIdx.x >= d) ? tmp[threadIdx.x - d] : 0;
    __syncthreads();
    tmp[threadIdx.x] += t;
    __syncthreads();
  }
  bpre[threadIdx.x] = tmp[threadIdx.x] - v;       // exclusive block prefix
}

__global__ __launch_bounds__(256)
void scan3(int* __restrict__ offs, const int* __restrict__ bpre) {
  int i = blockIdx.x * 256 + threadIdx.x;
  offs[i] += bpre[blockIdx.x];
}

__global__ __launch_bounds__(256)
void scatter_k(const int* __restrict__ ei, int* __restrict__ offs,
               int* __restrict__ sorted) {
  int e = blockIdx.x * 256 + threadIdx.x;
  if (e >= N_EDGES) return;
  int d = ei[N_EDGES + e];
  int pos = atomicAdd(&offs[d], 1);
  sorted[pos] = e;
}

// ---------------------------------------------------------------------------
// Edge MLP — barrier-free, wave owns 16 dst-sorted edges end-to-end.
// Epilogue: run-length segmented reduction over equal-dst rows -> one
// atomicAdd per (run, feature) instead of per (edge, feature).
// ---------------------------------------------------------------------------
#define LDA_E 168   // 160 + 8 pad shorts; row = 336 B (16B aligned)
#define LDH   264   // 256 + 8 pad shorts; row = 528 B (16B aligned)
#define SLAB  (16 * LDH)   // 4224 shorts = 8448 B per wave
#define LDM   68    // fp32 stride of epilogue tile (padded: conflict-free)

__global__ __launch_bounds__(256, 4)
void edge_mlp(const float* __restrict__ h, const float* __restrict__ ea,
              const int* __restrict__ ei, const int* __restrict__ sorted,
              const short* __restrict__ w1f, const float* __restrict__ b1,
              const short* __restrict__ w2f, const float* __restrict__ b2,
              float* __restrict__ agg) {
  __shared__ __align__(16) short slab[4 * SLAB];

  const int tid  = threadIdx.x;
  const int lane = tid & 63;
  const int wave = tid >> 6;
  const int col  = lane & 15;
  const int quad = lane >> 4;
  const int eb   = blockIdx.x * 64 + wave * 16;   // this wave's 16 sorted slots
  short* sA = slab + wave * SLAB;                 // [16][LDA_E] input tile
  short* sH = slab + wave * SLAB;                 // [16][LDH] hidden (reused)
  int*   ids = (int*)((char*)sA + 16 * LDA_E * 2); // 32 ints @ byte 5376

  // ---- resolve sorted edge ids -> src/dst into wave-local LDS
  if (lane < 32) {
    int e0 = sorted[eb + (lane & 15)];
    ids[lane] = (lane < 16) ? ei[e0] : ei[N_EDGES + e0];
  }

  // ---- stage: 16 edges x 160 fp32 (40 float4/edge) -> bf16 LDS
#pragma unroll
  for (int it = 0; it < 10; ++it) {
    int idx = it * 64 + lane;       // 0..639
    int e   = idx / 40;
    int j   = idx - e * 40;
    int k   = j * 4;
    float4v v;
    if (k < 64) {
      int d = ids[16 + e];
      v = *(const float4v*)(h + (size_t)d * D_MODEL + k);
    } else if (k < 128) {
      int s = ids[e];
      v = *(const float4v*)(h + (size_t)s * D_MODEL + (k - 64));
    } else {
      int e0 = sorted[eb + e];
      v = *(const float4v*)(ea + (size_t)e0 * 32 + (k - 128));
    }
    short* p = &sA[e * LDA_E + k];
    p[0] = f2bf(v.x); p[1] = f2bf(v.y); p[2] = f2bf(v.z); p[3] = f2bf(v.w);
  }

  // ---- GEMM1: [16,160] x [160,256], wave-private
  f32x4 acc[16];
#pragma unroll
  for (int nt = 0; nt < 16; ++nt) acc[nt] = (f32x4){0.f, 0.f, 0.f, 0.f};

#pragma unroll
  for (int kt = 0; kt < 5; ++kt) {
    short8 af = *(const short8*)&sA[col * LDA_E + kt * 32 + quad * 8];
#pragma unroll
    for (int nt = 0; nt < 16; ++nt) {
      short8 bf = *(const short8*)(w1f + (size_t)((kt * 16 + nt) * 64 + lane) * 8);
      acc[nt] = mfma16(af, bf, acc[nt]);
    }
  }

  // ---- snapshot dst list to registers BEFORE sH overwrites the ids area
  int dlist[16];
#pragma unroll
  for (int r = 0; r < 16; ++r) dlist[r] = ids[16 + r];

  // ---- bias + silu -> hidden (overwrites slab; wave-local ordering)
#pragma unroll
  for (int nt = 0; nt < 16; ++nt) {
    const int n = nt * 16 + col;
    const float bias = b1[n];
#pragma unroll
    for (int r = 0; r < 4; ++r) {
      const int row = quad * 4 + r;
      float x = acc[nt][r] + bias;
      float s = x / (1.0f + __expf(-x));
      sH[row * LDH + n] = f2bf(s);
    }
  }

  // ---- GEMM2: [16,256] x [256,64]
  f32x4 acc2[4];
#pragma unroll
  for (int nt = 0; nt < 4; ++nt) acc2[nt] = (f32x4){0.f, 0.f, 0.f, 0.f};

#pragma unroll
  for (int kt = 0; kt < 8; ++kt) {
    short8 af = *(const short8*)&sH[col * LDH + kt * 32 + quad * 8];
#pragma unroll
    for (int nt = 0; nt < 4; ++nt) {
      short8 bf = *(const short8*)(w2f + (size_t)((kt * 4 + nt) * 64 + lane) * 8);
      acc2[nt] = mfma16(af, bf, acc2[nt]);
    }
  }

  // ---- epilogue: bias -> LDS tile [16][LDM] fp32, run-reduce, atomic per run
  float* sM = (float*)sA;   // 16 * 68 * 4 = 4352 B (slab free after GEMM2)
#pragma unroll
  for (int nt = 0; nt < 4; ++nt) {
    const int n = nt * 16 + col;
    const float bias = b2[n];
#pragma unroll
    for (int r = 0; r < 4; ++r)
      sM[(quad * 4 + r) * LDM + n] = acc2[nt][r] + bias;
  }

  float sum = 0.f;
  int prev = dlist[0];
#pragma unroll
  for (int r = 0; r < 16; ++r) {
    float v = sM[r * LDM + lane];
    if (dlist[r] != prev) {            // wave-uniform branch (dlist is uniform)
      atomicAdd(agg + (size_t)prev * D_MODEL + lane, sum);
      sum = 0.f; prev = dlist[r];
    }
    sum += v;
  }
  atomicAdd(agg + (size_t)prev * D_MODEL + lane, sum);
}

// ---------------------------------------------------------------------------
// Node MLP — barrier-free wave-private, 16 nodes per wave.
// ---------------------------------------------------------------------------
#define LDA_N 136   // 128 + 8 pad shorts; row = 272 B

__global__ __launch_bounds__(256, 4)
void node_mlp(const float* __restrict__ h, const float* __restrict__ agg,
              const short* __restrict__ w1f, const float* __restrict__ b1,
              const short* __restrict__ w2f, const float* __restrict__ b2,
              float* __restrict__ hnew) {
  __shared__ __align__(16) short slab[4 * SLAB];

  const int tid  = threadIdx.x;
  const int lane = tid & 63;
  const int wave = tid >> 6;
  const int col  = lane & 15;
  const int quad = lane >> 4;
  const int nb   = blockIdx.x * 64 + wave * 16;
  short* sA = slab + wave * SLAB;   // [16][LDA_N]
  short* sH = slab + wave * SLAB;   // [16][LDH]

#pragma unroll
  for (int it = 0; it < 8; ++it) {
    int idx = it * 64 + lane;     // 0..511
    int i   = idx >> 5;
    int j   = idx & 31;
    int k   = j * 4;
    int gi  = nb + i;
    if (gi >= N_NODES) gi = N_NODES - 1;   // clamp; OOB rows never stored
    float4v v = (k < 64) ? *(const float4v*)(h + (size_t)gi * D_MODEL + k)
                         : *(const float4v*)(agg + (size_t)gi * D_MODEL + (k - 64));
    short* p = &sA[i * LDA_N + k];
    p[0] = f2bf(v.x); p[1] = f2bf(v.y); p[2] = f2bf(v.z); p[3] = f2bf(v.w);
  }

  // ---- GEMM1: K=128
  f32x4 acc[16];
#pragma unroll
  for (int nt = 0; nt < 16; ++nt) acc[nt] = (f32x4){0.f, 0.f, 0.f, 0.f};

#pragma unroll
  for (int kt = 0; kt < 4; ++kt) {
    short8 af = *(const short8*)&sA[col * LDA_N + kt * 32 + quad * 8];
#pragma unroll
    for (int nt = 0; nt < 16; ++nt) {
      short8 bf = *(const short8*)(w1f + (size_t)((kt * 16 + nt) * 64 + lane) * 8);
      acc[nt] = mfma16(af, bf, acc[nt]);
    }
  }

#pragma unroll
  for (int nt = 0; nt < 16; ++nt) {
    const int n = nt * 16 + col;
    const float bias = b1[n];
#pragma unroll
    for (int r = 0; r < 4; ++r) {
      const int row = quad * 4 + r;
      float x = acc[nt][r] + bias;
      float s = x / (1.0f + __expf(-x));
      sH[row * LDH + n] = f2bf(s);
    }
  }

  // ---- GEMM2: K=256
  f32x4 acc2[4];
#pragma unroll
  for (int nt = 0; nt < 4; ++nt) acc2[nt] = (f32x4){0.f, 0.f, 0.f, 0.f};

#pragma unroll
  for (int kt = 0; kt < 8; ++kt) {
    short8 af = *(const short8*)&sH[col * LDH + kt * 32 + quad * 8];
#pragma unroll
    for (int nt = 0; nt < 4; ++nt) {
      short8 bf = *(const short8*)(w2f + (size_t)((kt * 4 + nt) * 64 + lane) * 8);
      acc2[nt] = mfma16(af, bf, acc2[nt]);
    }
  }

  // ---- h_new = h + dh
#pragma unroll
  for (int r = 0; r < 4; ++r) {
    const int gi = nb + quad * 4 + r;
    if (gi < N_NODES) {
#pragma unroll
      for (int nt = 0; nt < 4; ++nt) {
        const int n = nt * 16 + col;
        hnew[(size_t)gi * D_MODEL + n] =
            h[(size_t)gi * D_MODEL + n] + acc2[nt][r] + b2[n];
      }
    }
  }
}

// ---------------------------------------------------------------------------
// GraphNorm — single-pass stats (S1, S2, count), batch is sorted.
// ---------------------------------------------------------------------------
#define GN_CHUNK 64

__global__ __launch_bounds__(64)
void gn_stats(const float* __restrict__ x, const int* __restrict__ batch,
              float* __restrict__ s1, float* __restrict__ s2,
              float* __restrict__ cnt) {
  const int f = threadIdx.x;
  const int base = blockIdx.x * GN_CHUNK;
  const int end = (base + GN_CHUNK < N_NODES) ? base + GN_CHUNK : N_NODES;
  float a1 = 0.f, a2 = 0.f;
  int cur = batch[base], c0 = base;
  for (int i = base; i < end; ++i) {
    int g = batch[i];
    if (g != cur) {
      atomicAdd(&s1[cur * D_MODEL + f], a1);
      atomicAdd(&s2[cur * D_MODEL + f], a2);
      if (f == 0) atomicAdd(&cnt[cur], (float)(i - c0));
      a1 = 0.f; a2 = 0.f; cur = g; c0 = i;
    }
    float v = x[(size_t)i * D_MODEL + f];
    a1 += v; a2 += v * v;
  }
  atomicAdd(&s1[cur * D_MODEL + f], a1);
  atomicAdd(&s2[cur * D_MODEL + f], a2);
  if (f == 0) atomicAdd(&cnt[cur], (float)(end - c0));
}

__global__ __launch_bounds__(256)
void gn_norm(float* __restrict__ x, const int* __restrict__ batch,
             const float* __restrict__ s1, const float* __restrict__ s2,
             const float* __restrict__ cnt, const float* __restrict__ alpha,
             const float* __restrict__ weight, const float* __restrict__ bias) {
  int idx = blockIdx.x * 256 + threadIdx.x;
  if (idx >= N_NODES * D_MODEL) return;
  int i = idx >> 6, f = idx & 63;
  int g = batch[i];
  float c = fmaxf(cnt[g], 1.f);
  float m   = s1[g * D_MODEL + f] / c;
  float ex2 = s2[g * D_MODEL + f] / c;
  float a = alpha[f];
  float var = ex2 - 2.f * a * m * m + a * a * m * m;
  float hc = x[idx] - a * m;
  x[idx] = weight[f] * hc * rsqrtf(var + EPS_GN) + bias[f];
}

// ---------------------------------------------------------------------------
extern "C" void kernel_launch(void* const* d_in, const int* in_sizes, int n_in,
                              void* d_out, int out_size, void* d_ws, size_t ws_size,
                              hipStream_t stream) {
  const float* h     = (const float*)d_in[0];
  const float* ea    = (const float*)d_in[1];
  const int*   ei    = (const int*)d_in[2];   // [2][E], row0=src, row1=dst
  const int*   batch = (const int*)d_in[3];
  const float* mw1   = (const float*)d_in[4];
  const float* mb1   = (const float*)d_in[5];
  const float* mw2   = (const float*)d_in[6];
  const float* mb2   = (const float*)d_in[7];
  const float* uw1   = (const float*)d_in[8];
  const float* ub1   = (const float*)d_in[9];
  const float* uw2   = (const float*)d_in[10];
  const float* ub2   = (const float*)d_in[11];
  const float* gw    = (const float*)d_in[12];
  const float* gb    = (const float*)d_in[13];
  const float* ga    = (const float*)d_in[14];

  char* ws = (char*)d_ws;
  float* agg    = (float*)(ws + 0);             // 12,800,000 B
  short* w1f    = (short*)(ws + 12800000);      //     81,920 B
  short* w2f    = (short*)(ws + 12881920);      //     32,768 B
  short* u1f    = (short*)(ws + 12914688);      //     65,536 B
  short* u2f    = (short*)(ws + 12980224);      //     32,768 B
  float* s1     = (float*)(ws + 13012992);      //     16,384 B
  float* s2     = (float*)(ws + 13029376);      //     16,384 B
  float* cnt    = (float*)(ws + 13045760);      //        256 B
  int*   hist   = (int*)  (ws + 13046016);      //    200,704 B (50176 ints)
  int*   offs   = (int*)  (ws + 13246720);      //    200,704 B
  int*   bsums  = (int*)  (ws + 13447424);      //      1,024 B
  int*   bpre   = (int*)  (ws + 13448448);      //      1,024 B
  int*   sorted = (int*)  (ws + 13449472);      //  3,200,000 B  -> end 16,649,472

  hipMemsetAsync(agg, 0, 12800000, stream);
  hipMemsetAsync(ws + 13012992, 0, 33024, stream);
  hipMemsetAsync(hist, 0, 200704, stream);

  prep_all<<<52, 256, 0, stream>>>(mw1, mw2, uw1, uw2, w1f, w2f, u1f, u2f);

  // counting sort of edges by dst
  hist_k  <<<(N_EDGES + 255) / 256, 256, 0, stream>>>(ei, hist);
  scan1   <<<NB_SCAN, 256, 0, stream>>>(hist, offs, bsums);
  scan2   <<<1, 256, 0, stream>>>(bsums, bpre);
  scan3   <<<NB_SCAN, 256, 0, stream>>>(offs, bpre);
  scatter_k<<<(N_EDGES + 255) / 256, 256, 0, stream>>>(ei, offs, sorted);

  edge_mlp<<<N_EDGES / 64, 256, 0, stream>>>(h, ea, ei, sorted,
                                             w1f, mb1, w2f, mb2, agg);

  node_mlp<<<(N_NODES + 63) / 64, 256, 0, stream>>>(h, agg, u1f, ub1, u2f, ub2,
                                                    (float*)d_out);

  int gn_blocks = (N_NODES + GN_CHUNK - 1) / GN_CHUNK;
  gn_stats<<<gn_blocks, 64, 0, stream>>>((const float*)d_out, batch, s1, s2, cnt);
  gn_norm<<<(N_NODES * D_MODEL + 255) / 256, 256, 0, stream>>>(
      (float*)d_out, batch, s1, s2, cnt, ga, gw, gb);
}

// Round 5
// 685.194 us; speedup vs baseline: 1.2470x; 1.1599x over previous
//
#include <hip/hip_runtime.h>
#include <hip/hip_bf16.h>
#include <stdint.h>

#define N_NODES   50000
#define N_EDGES   800000
#define D_MODEL   64
#define D_HIDDEN  256
#define N_GRAPHS  64
#define EPS_GN    1e-5f

#define NBINS_PAD 50176            // 196 * 256, zero-padded histogram
#define NB_SCAN   196

typedef __attribute__((ext_vector_type(8))) short short8;   // 8 bf16 (4 VGPRs)
typedef __attribute__((ext_vector_type(4))) float f32x4;
typedef __attribute__((ext_vector_type(4))) float float4v;

static __device__ __forceinline__ short f2bf(float f) {
  union { float f; uint32_t u; } v; v.f = f;
  uint32_t r = (v.u + 0x7fffu + ((v.u >> 16) & 1u)) >> 16;   // RNE
  return (short)(uint16_t)r;
}

static __device__ __forceinline__ f32x4 mfma16(short8 a, short8 b, f32x4 c) {
  return __builtin_amdgcn_mfma_f32_16x16x32_bf16(a, b, c, 0, 0, 0);
}

// ---------------------------------------------------------------------------
// Weight prep (all 4 mats): w [K][Nn] fp32 -> bf16 MFMA B-fragment layout
// [kt][nt][lane][8]; frag elem j of lane L = w[kt*32+(L>>4)*8+j][nt*16+(L&15)]
// ---------------------------------------------------------------------------
__global__ void prep_all(const float* __restrict__ mw1, const float* __restrict__ mw2,
                         const float* __restrict__ uw1, const float* __restrict__ uw2,
                         short* __restrict__ w1f, short* __restrict__ w2f,
                         short* __restrict__ u1f, short* __restrict__ u2f) {
  int b = blockIdx.x;
  const float* w; short* out; int K, Nn, t;
  if (b < 20)      { w = mw1; out = w1f; K = 160; Nn = 256; t = b * 256 + threadIdx.x; }
  else if (b < 28) { w = mw2; out = w2f; K = 256; Nn = 64;  t = (b - 20) * 256 + threadIdx.x; }
  else if (b < 44) { w = uw1; out = u1f; K = 128; Nn = 256; t = (b - 28) * 256 + threadIdx.x; }
  else             { w = uw2; out = u2f; K = 256; Nn = 64;  t = (b - 44) * 256 + threadIdx.x; }
  int total = (K >> 5) * (Nn >> 4) * 64;
  if (t >= total) return;
  int lane = t & 63;
  int rest = t >> 6;
  int ntN = Nn >> 4;
  int nt = rest % ntN;
  int kt = rest / ntN;
  int n  = nt * 16 + (lane & 15);
  int k0 = kt * 32 + (lane >> 4) * 8;
  short* o = out + (size_t)t * 8;
#pragma unroll
  for (int j = 0; j < 8; ++j)
    o[j] = f2bf(w[(size_t)(k0 + j) * Nn + n]);
}

// ---------------------------------------------------------------------------
// Counting sort of edges by dst: hist -> 2-level exclusive scan -> scatter.
// ---------------------------------------------------------------------------
__global__ __launch_bounds__(256)
void hist_k(const int* __restrict__ ei, int* __restrict__ hist) {
  int e = blockIdx.x * 256 + threadIdx.x;
  if (e >= N_EDGES) return;
  atomicAdd(&hist[ei[N_EDGES + e]], 1);
}

__global__ __launch_bounds__(256)
void scan1(const int* __restrict__ hist, int* __restrict__ offs,
           int* __restrict__ bsums) {
  __shared__ int tmp[256];
  int i = blockIdx.x * 256 + threadIdx.x;
  int v = hist[i];
  tmp[threadIdx.x] = v;
  __syncthreads();
#pragma unroll
  for (int d = 1; d < 256; d <<= 1) {
    int t = (threadIdx.x >= d) ? tmp[threadIdx.x - d] : 0;
    __syncthreads();
    tmp[threadIdx.x] += t;
    __syncthreads();
  }
  offs[i] = tmp[threadIdx.x] - v;                 // exclusive within block
  if (threadIdx.x == 255) bsums[blockIdx.x] = tmp[255];
}

__global__ __launch_bounds__(256)
void scan2(const int* __restrict__ bsums, int* __restrict__ bpre) {
  __shared__ int tmp[256];
  int v = (threadIdx.x < NB_SCAN) ? bsums[threadIdx.x] : 0;
  tmp[threadIdx.x] = v;
  __syncthreads();
#pragma unroll
  for (int d = 1; d < 256; d <<= 1) {
    int t = (threadIdx.x >= d) ? tmp[threadIdx.x - d] : 0;
    __syncthreads();
    tmp[threadIdx.x] += t;
    __syncthreads();
  }
  bpre[threadIdx.x] = tmp[threadIdx.x] - v;       // exclusive block prefix
}

__global__ __launch_bounds__(256)
void scan3(int* __restrict__ offs, const int* __restrict__ bpre) {
  int i = blockIdx.x * 256 + threadIdx.x;
  offs[i] += bpre[blockIdx.x];
}

__global__ __launch_bounds__(256)
void scatter_k(const int* __restrict__ ei, int* __restrict__ offs,
               int* __restrict__ sorted) {
  int e = blockIdx.x * 256 + threadIdx.x;
  if (e >= N_EDGES) return;
  int d = ei[N_EDGES + e];
  int pos = atomicAdd(&offs[d], 1);
  sorted[pos] = e;
}

// ---------------------------------------------------------------------------
// Edge MLP — block-cooperative (64 dst-sorted edges / block, 3 barriers).
// GEMM1: waves split N (4 n-tiles each, acc[4][4], bf[2][4] B-prefetch) so
// weight traffic is 112 KB per 64 edges (1.4 GB total, L2-resident), and
// register peak stays ~130 (no spill under launch_bounds(256,2)).
// GEMM2: waves split N (1 n-tile each), C -> LDS tile, then each wave
// run-reduces its own staged 16 rows -> one atomic per (run, feature).
// ---------------------------------------------------------------------------
#define LDA_E 168   // 160 + 8 pad shorts; row = 336 B (16B aligned)
#define LDH   264   // 256 + 8 pad shorts; row = 528 B (16B aligned)
#define LDC   68    // fp32 stride of C tile (aliases sA after GEMM1)

__global__ __launch_bounds__(256, 2)
void edge_mlp(const float* __restrict__ h, const float* __restrict__ ea,
              const int* __restrict__ ei, const int* __restrict__ sorted,
              const short* __restrict__ w1f, const float* __restrict__ b1,
              const short* __restrict__ w2f, const float* __restrict__ b2,
              float* __restrict__ agg) {
  __shared__ __align__(16) short sA[64 * LDA_E];   // 21504 B (C tile aliases)
  __shared__ __align__(16) short sH[64 * LDH];     // 33792 B
  __shared__ int s_ids[4][32];                     // per-wave src[16], dst[16]

  const int tid  = threadIdx.x;
  const int lane = tid & 63;
  const int wave = tid >> 6;
  const int col  = lane & 15;
  const int quad = lane >> 4;
  const int eb   = blockIdx.x * 64 + wave * 16;    // this wave's 16 sorted slots

  // ---- resolve sorted edge ids -> src/dst (wave-local; read by same wave)
  if (lane < 32) {
    int e0 = sorted[eb + (lane & 15)];
    s_ids[wave][lane] = (lane < 16) ? ei[e0] : ei[N_EDGES + e0];
  }

  // ---- stage: each wave its 16 edges x 160 fp32 (40 float4/edge) -> bf16
#pragma unroll
  for (int it = 0; it < 10; ++it) {
    int idx = it * 64 + lane;       // 0..639
    int e   = idx / 40;
    int j   = idx - e * 40;
    int k   = j * 4;
    float4v v;
    if (k < 64) {
      int d = s_ids[wave][16 + e];
      v = *(const float4v*)(h + (size_t)d * D_MODEL + k);
    } else if (k < 128) {
      int s = s_ids[wave][e];
      v = *(const float4v*)(h + (size_t)s * D_MODEL + (k - 64));
    } else {
      int e0 = sorted[eb + e];
      v = *(const float4v*)(ea + (size_t)e0 * 32 + (k - 128));
    }
    short* p = &sA[(wave * 16 + e) * LDA_E + k];
    p[0] = f2bf(v.x); p[1] = f2bf(v.y); p[2] = f2bf(v.z); p[3] = f2bf(v.w);
  }
  __syncthreads();

  // ---- GEMM1: [64,160] x [160,256]; wave covers n-tiles [4w, 4w+4)
  f32x4 acc[4][4];
#pragma unroll
  for (int mt = 0; mt < 4; ++mt)
#pragma unroll
    for (int nt = 0; nt < 4; ++nt)
      acc[mt][nt] = (f32x4){0.f, 0.f, 0.f, 0.f};

  short8 bf[2][4];
#pragma unroll
  for (int nt = 0; nt < 4; ++nt)
    bf[0][nt] = *(const short8*)(w1f + (size_t)((wave * 4 + nt) * 64 + lane) * 8);

#pragma unroll
  for (int kt = 0; kt < 5; ++kt) {
    if (kt < 4) {
#pragma unroll
      for (int nt = 0; nt < 4; ++nt)
        bf[(kt + 1) & 1][nt] = *(const short8*)(
            w1f + (size_t)(((kt + 1) * 16 + wave * 4 + nt) * 64 + lane) * 8);
    }
    short8 af[4];
#pragma unroll
    for (int mt = 0; mt < 4; ++mt)
      af[mt] = *(const short8*)&sA[(mt * 16 + col) * LDA_E + kt * 32 + quad * 8];
#pragma unroll
    for (int nt = 0; nt < 4; ++nt)
#pragma unroll
      for (int mt = 0; mt < 4; ++mt)
        acc[mt][nt] = mfma16(af[mt], bf[kt & 1][nt], acc[mt][nt]);
  }

  // ---- bias + silu -> sH (wave writes its 64-col slice, all 64 rows)
#pragma unroll
  for (int nt = 0; nt < 4; ++nt) {
    const int n = (wave * 4 + nt) * 16 + col;
    const float bias = b1[n];
#pragma unroll
    for (int mt = 0; mt < 4; ++mt) {
#pragma unroll
      for (int r = 0; r < 4; ++r) {
        const int row = mt * 16 + quad * 4 + r;
        float x = acc[mt][nt][r] + bias;
        float s = x / (1.0f + __expf(-x));
        sH[row * LDH + n] = f2bf(s);
      }
    }
  }
  __syncthreads();

  // ---- GEMM2: [64,256] x [256,64]; wave covers n-tile `wave` (16 cols)
  f32x4 acc2[4];
#pragma unroll
  for (int mt = 0; mt < 4; ++mt) acc2[mt] = (f32x4){0.f, 0.f, 0.f, 0.f};

  short8 bf2[2];
  bf2[0] = *(const short8*)(w2f + (size_t)(wave * 64 + lane) * 8);

#pragma unroll
  for (int kt = 0; kt < 8; ++kt) {
    if (kt < 7)
      bf2[(kt + 1) & 1] = *(const short8*)(
          w2f + (size_t)(((kt + 1) * 4 + wave) * 64 + lane) * 8);
    short8 af[4];
#pragma unroll
    for (int mt = 0; mt < 4; ++mt)
      af[mt] = *(const short8*)&sH[(mt * 16 + col) * LDH + kt * 32 + quad * 8];
#pragma unroll
    for (int mt = 0; mt < 4; ++mt)
      acc2[mt] = mfma16(af[mt], bf2[kt & 1], acc2[mt]);
  }

  // ---- dump C (+bias) into LDS tile aliasing sA (sA dead after barrier #2)
  float* sC = (float*)sA;   // [64][LDC] fp32 = 17408 B <= 21504 B
  {
    const int n = wave * 16 + col;
    const float bias = b2[n];
#pragma unroll
    for (int mt = 0; mt < 4; ++mt)
#pragma unroll
      for (int r = 0; r < 4; ++r)
        sC[(mt * 16 + quad * 4 + r) * LDC + n] = acc2[mt][r] + bias;
  }
  __syncthreads();

  // ---- run-reduce own 16 rows (dst-sorted): one atomic per run per feature
  float sum = 0.f;
  int prev = s_ids[wave][16];
#pragma unroll
  for (int r = 0; r < 16; ++r) {
    float v = sC[(wave * 16 + r) * LDC + lane];
    int d = s_ids[wave][16 + r];          // LDS broadcast -> wave-uniform
    if (d != prev) {
      atomicAdd(agg + (size_t)prev * D_MODEL + lane, sum);
      sum = 0.f; prev = d;
    }
    sum += v;
  }
  atomicAdd(agg + (size_t)prev * D_MODEL + lane, sum);
}

// ---------------------------------------------------------------------------
// Node MLP — same block-cooperative structure, 64 nodes / block.
// ---------------------------------------------------------------------------
#define LDA_N 136   // 128 + 8 pad shorts; row = 272 B

__global__ __launch_bounds__(256, 2)
void node_mlp(const float* __restrict__ h, const float* __restrict__ agg,
              const short* __restrict__ w1f, const float* __restrict__ b1,
              const short* __restrict__ w2f, const float* __restrict__ b2,
              float* __restrict__ hnew) {
  __shared__ __align__(16) short sA[64 * LDA_N];   // 17408 B
  __shared__ __align__(16) short sH[64 * LDH];     // 33792 B

  const int tid  = threadIdx.x;
  const int lane = tid & 63;
  const int wave = tid >> 6;
  const int col  = lane & 15;
  const int quad = lane >> 4;
  const int nb   = blockIdx.x * 64;

  // ---- stage: each wave its 16 nodes x 128 fp32 (32 float4/node)
#pragma unroll
  for (int it = 0; it < 8; ++it) {
    int idx = it * 64 + lane;     // 0..511
    int i   = idx >> 5;           // 0..15
    int j   = idx & 31;
    int k   = j * 4;
    int row = wave * 16 + i;
    int gi  = nb + row;
    if (gi >= N_NODES) gi = N_NODES - 1;   // clamp; OOB rows never stored
    float4v v = (k < 64) ? *(const float4v*)(h + (size_t)gi * D_MODEL + k)
                         : *(const float4v*)(agg + (size_t)gi * D_MODEL + (k - 64));
    short* p = &sA[row * LDA_N + k];
    p[0] = f2bf(v.x); p[1] = f2bf(v.y); p[2] = f2bf(v.z); p[3] = f2bf(v.w);
  }
  __syncthreads();

  // ---- GEMM1: K=128; wave covers n-tiles [4w, 4w+4)
  f32x4 acc[4][4];
#pragma unroll
  for (int mt = 0; mt < 4; ++mt)
#pragma unroll
    for (int nt = 0; nt < 4; ++nt)
      acc[mt][nt] = (f32x4){0.f, 0.f, 0.f, 0.f};

  short8 bf[2][4];
#pragma unroll
  for (int nt = 0; nt < 4; ++nt)
    bf[0][nt] = *(const short8*)(w1f + (size_t)((wave * 4 + nt) * 64 + lane) * 8);

#pragma unroll
  for (int kt = 0; kt < 4; ++kt) {
    if (kt < 3) {
#pragma unroll
      for (int nt = 0; nt < 4; ++nt)
        bf[(kt + 1) & 1][nt] = *(const short8*)(
            w1f + (size_t)(((kt + 1) * 16 + wave * 4 + nt) * 64 + lane) * 8);
    }
    short8 af[4];
#pragma unroll
    for (int mt = 0; mt < 4; ++mt)
      af[mt] = *(const short8*)&sA[(mt * 16 + col) * LDA_N + kt * 32 + quad * 8];
#pragma unroll
    for (int nt = 0; nt < 4; ++nt)
#pragma unroll
      for (int mt = 0; mt < 4; ++mt)
        acc[mt][nt] = mfma16(af[mt], bf[kt & 1][nt], acc[mt][nt]);
  }

#pragma unroll
  for (int nt = 0; nt < 4; ++nt) {
    const int n = (wave * 4 + nt) * 16 + col;
    const float bias = b1[n];
#pragma unroll
    for (int mt = 0; mt < 4; ++mt) {
#pragma unroll
      for (int r = 0; r < 4; ++r) {
        const int row = mt * 16 + quad * 4 + r;
        float x = acc[mt][nt][r] + bias;
        float s = x / (1.0f + __expf(-x));
        sH[row * LDH + n] = f2bf(s);
      }
    }
  }
  __syncthreads();

  // ---- GEMM2: K=256; wave covers n-tile `wave`
  f32x4 acc2[4];
#pragma unroll
  for (int mt = 0; mt < 4; ++mt) acc2[mt] = (f32x4){0.f, 0.f, 0.f, 0.f};

  short8 bf2[2];
  bf2[0] = *(const short8*)(w2f + (size_t)(wave * 64 + lane) * 8);

#pragma unroll
  for (int kt = 0; kt < 8; ++kt) {
    if (kt < 7)
      bf2[(kt + 1) & 1] = *(const short8*)(
          w2f + (size_t)(((kt + 1) * 4 + wave) * 64 + lane) * 8);
    short8 af[4];
#pragma unroll
    for (int mt = 0; mt < 4; ++mt)
      af[mt] = *(const short8*)&sH[(mt * 16 + col) * LDH + kt * 32 + quad * 8];
#pragma unroll
    for (int mt = 0; mt < 4; ++mt)
      acc2[mt] = mfma16(af[mt], bf2[kt & 1], acc2[mt]);
  }

  // ---- h_new = h + dh  (wave writes its 16-col slice for all 64 rows)
  {
    const int n = wave * 16 + col;
    const float bias = b2[n];
#pragma unroll
    for (int mt = 0; mt < 4; ++mt) {
#pragma unroll
      for (int r = 0; r < 4; ++r) {
        const int gi = nb + mt * 16 + quad * 4 + r;
        if (gi < N_NODES)
          hnew[(size_t)gi * D_MODEL + n] =
              h[(size_t)gi * D_MODEL + n] + acc2[mt][r] + bias;
      }
    }
  }
}

// ---------------------------------------------------------------------------
// GraphNorm — single-pass stats (S1, S2, count), batch is sorted.
// ---------------------------------------------------------------------------
#define GN_CHUNK 64

__global__ __launch_bounds__(64)
void gn_stats(const float* __restrict__ x, const int* __restrict__ batch,
              float* __restrict__ s1, float* __restrict__ s2,
              float* __restrict__ cnt) {
  const int f = threadIdx.x;
  const int base = blockIdx.x * GN_CHUNK;
  const int end = (base + GN_CHUNK < N_NODES) ? base + GN_CHUNK : N_NODES;
  float a1 = 0.f, a2 = 0.f;
  int cur = batch[base], c0 = base;
  for (int i = base; i < end; ++i) {
    int g = batch[i];
    if (g != cur) {
      atomicAdd(&s1[cur * D_MODEL + f], a1);
      atomicAdd(&s2[cur * D_MODEL + f], a2);
      if (f == 0) atomicAdd(&cnt[cur], (float)(i - c0));
      a1 = 0.f; a2 = 0.f; cur = g; c0 = i;
    }
    float v = x[(size_t)i * D_MODEL + f];
    a1 += v; a2 += v * v;
  }
  atomicAdd(&s1[cur * D_MODEL + f], a1);
  atomicAdd(&s2[cur * D_MODEL + f], a2);
  if (f == 0) atomicAdd(&cnt[cur], (float)(end - c0));
}

__global__ __launch_bounds__(256)
void gn_norm(float* __restrict__ x, const int* __restrict__ batch,
             const float* __restrict__ s1, const float* __restrict__ s2,
             const float* __restrict__ cnt, const float* __restrict__ alpha,
             const float* __restrict__ weight, const float* __restrict__ bias) {
  int idx = blockIdx.x * 256 + threadIdx.x;
  if (idx >= N_NODES * D_MODEL) return;
  int i = idx >> 6, f = idx & 63;
  int g = batch[i];
  float c = fmaxf(cnt[g], 1.f);
  float m   = s1[g * D_MODEL + f] / c;
  float ex2 = s2[g * D_MODEL + f] / c;
  float a = alpha[f];
  float var = ex2 - 2.f * a * m * m + a * a * m * m;
  float hc = x[idx] - a * m;
  x[idx] = weight[f] * hc * rsqrtf(var + EPS_GN) + bias[f];
}

// ---------------------------------------------------------------------------
extern "C" void kernel_launch(void* const* d_in, const int* in_sizes, int n_in,
                              void* d_out, int out_size, void* d_ws, size_t ws_size,
                              hipStream_t stream) {
  const float* h     = (const float*)d_in[0];
  const float* ea    = (const float*)d_in[1];
  const int*   ei    = (const int*)d_in[2];   // [2][E], row0=src, row1=dst
  const int*   batch = (const int*)d_in[3];
  const float* mw1   = (const float*)d_in[4];
  const float* mb1   = (const float*)d_in[5];
  const float* mw2   = (const float*)d_in[6];
  const float* mb2   = (const float*)d_in[7];
  const float* uw1   = (const float*)d_in[8];
  const float* ub1   = (const float*)d_in[9];
  const float* uw2   = (const float*)d_in[10];
  const float* ub2   = (const float*)d_in[11];
  const float* gw    = (const float*)d_in[12];
  const float* gb    = (const float*)d_in[13];
  const float* ga    = (const float*)d_in[14];

  char* ws = (char*)d_ws;
  float* agg    = (float*)(ws + 0);             // 12,800,000 B
  short* w1f    = (short*)(ws + 12800000);      //     81,920 B
  short* w2f    = (short*)(ws + 12881920);      //     32,768 B
  short* u1f    = (short*)(ws + 12914688);      //     65,536 B
  short* u2f    = (short*)(ws + 12980224);      //     32,768 B
  float* s1     = (float*)(ws + 13012992);      //     16,384 B
  float* s2     = (float*)(ws + 13029376);      //     16,384 B
  float* cnt    = (float*)(ws + 13045760);      //        256 B
  int*   hist   = (int*)  (ws + 13046016);      //    200,704 B (50176 ints)
  int*   offs   = (int*)  (ws + 13246720);      //    200,704 B
  int*   bsums  = (int*)  (ws + 13447424);      //      1,024 B
  int*   bpre   = (int*)  (ws + 13448448);      //      1,024 B
  int*   sorted = (int*)  (ws + 13449472);      //  3,200,000 B  -> end 16,649,472

  hipMemsetAsync(agg, 0, 12800000, stream);
  hipMemsetAsync(ws + 13012992, 0, 33024, stream);
  hipMemsetAsync(hist, 0, 200704, stream);

  prep_all<<<52, 256, 0, stream>>>(mw1, mw2, uw1, uw2, w1f, w2f, u1f, u2f);

  // counting sort of edges by dst
  hist_k  <<<(N_EDGES + 255) / 256, 256, 0, stream>>>(ei, hist);
  scan1   <<<NB_SCAN, 256, 0, stream>>>(hist, offs, bsums);
  scan2   <<<1, 256, 0, stream>>>(bsums, bpre);
  scan3   <<<NB_SCAN, 256, 0, stream>>>(offs, bpre);
  scatter_k<<<(N_EDGES + 255) / 256, 256, 0, stream>>>(ei, offs, sorted);

  edge_mlp<<<N_EDGES / 64, 256, 0, stream>>>(h, ea, ei, sorted,
                                             w1f, mb1, w2f, mb2, agg);

  node_mlp<<<(N_NODES + 63) / 64, 256, 0, stream>>>(h, agg, u1f, ub1, u2f, ub2,
                                                    (float*)d_out);

  int gn_blocks = (N_NODES + GN_CHUNK - 1) / GN_CHUNK;
  gn_stats<<<gn_blocks, 64, 0, stream>>>((const float*)d_out, batch, s1, s2, cnt);
  gn_norm<<<(N_NODES * D_MODEL + 255) / 256, 256, 0, stream>>>(
      (float*)d_out, batch, s1, s2, cnt, ga, gw, gb);
}

// Round 6
// 574.159 us; speedup vs baseline: 1.4882x; 1.1934x over previous
//
#include <hip/hip_runtime.h>
#include <hip/hip_bf16.h>
#include <stdint.h>

#define N_NODES   50000
#define N_EDGES   800000
#define D_MODEL   64
#define D_HIDDEN  256
#define N_GRAPHS  64
#define EPS_GN    1e-5f

#define NBINS_PAD 50176            // 196 * 256, zero-padded histogram
#define NB_SCAN   196

typedef __attribute__((ext_vector_type(8))) short short8;   // 8 bf16 (4 VGPRs)
typedef __attribute__((ext_vector_type(4))) float f32x4;
typedef __attribute__((ext_vector_type(4))) float float4v;

static __device__ __forceinline__ short f2bf(float f) {
  union { float f; uint32_t u; } v; v.f = f;
  uint32_t r = (v.u + 0x7fffu + ((v.u >> 16) & 1u)) >> 16;   // RNE
  return (short)(uint16_t)r;
}

// fast silu: hardware rcp (rel err ~2^-22 << bf16 rounding) instead of IEEE div
static __device__ __forceinline__ float silu_f(float x) {
  return x * __builtin_amdgcn_rcpf(1.0f + __expf(-x));
}

static __device__ __forceinline__ f32x4 mfma16(short8 a, short8 b, f32x4 c) {
  return __builtin_amdgcn_mfma_f32_16x16x32_bf16(a, b, c, 0, 0, 0);
}

// ---------------------------------------------------------------------------
// Weight prep (all 4 mats): w [K][Nn] fp32 -> bf16 MFMA B-fragment layout
// [kt][nt][lane][8]; frag elem j of lane L = w[kt*32+(L>>4)*8+j][nt*16+(L&15)]
// ---------------------------------------------------------------------------
__global__ void prep_all(const float* __restrict__ mw1, const float* __restrict__ mw2,
                         const float* __restrict__ uw1, const float* __restrict__ uw2,
                         short* __restrict__ w1f, short* __restrict__ w2f,
                         short* __restrict__ u1f, short* __restrict__ u2f) {
  int b = blockIdx.x;
  const float* w; short* out; int K, Nn, t;
  if (b < 20)      { w = mw1; out = w1f; K = 160; Nn = 256; t = b * 256 + threadIdx.x; }
  else if (b < 28) { w = mw2; out = w2f; K = 256; Nn = 64;  t = (b - 20) * 256 + threadIdx.x; }
  else if (b < 44) { w = uw1; out = u1f; K = 128; Nn = 256; t = (b - 28) * 256 + threadIdx.x; }
  else             { w = uw2; out = u2f; K = 256; Nn = 64;  t = (b - 44) * 256 + threadIdx.x; }
  int total = (K >> 5) * (Nn >> 4) * 64;
  if (t >= total) return;
  int lane = t & 63;
  int rest = t >> 6;
  int ntN = Nn >> 4;
  int nt = rest % ntN;
  int kt = rest / ntN;
  int n  = nt * 16 + (lane & 15);
  int k0 = kt * 32 + (lane >> 4) * 8;
  short* o = out + (size_t)t * 8;
#pragma unroll
  for (int j = 0; j < 8; ++j)
    o[j] = f2bf(w[(size_t)(k0 + j) * Nn + n]);
}

// ---------------------------------------------------------------------------
// Counting sort of edges by dst: hist -> 2-level exclusive scan -> scatter.
// ---------------------------------------------------------------------------
__global__ __launch_bounds__(256)
void hist_k(const int* __restrict__ ei, int* __restrict__ hist) {
  int e = blockIdx.x * 256 + threadIdx.x;
  if (e >= N_EDGES) return;
  atomicAdd(&hist[ei[N_EDGES + e]], 1);
}

__global__ __launch_bounds__(256)
void scan1(const int* __restrict__ hist, int* __restrict__ offs,
           int* __restrict__ bsums) {
  __shared__ int tmp[256];
  int i = blockIdx.x * 256 + threadIdx.x;
  int v = hist[i];
  tmp[threadIdx.x] = v;
  __syncthreads();
#pragma unroll
  for (int d = 1; d < 256; d <<= 1) {
    int t = (threadIdx.x >= d) ? tmp[threadIdx.x - d] : 0;
    __syncthreads();
    tmp[threadIdx.x] += t;
    __syncthreads();
  }
  offs[i] = tmp[threadIdx.x] - v;                 // exclusive within block
  if (threadIdx.x == 255) bsums[blockIdx.x] = tmp[255];
}

__global__ __launch_bounds__(256)
void scan2(const int* __restrict__ bsums, int* __restrict__ bpre) {
  __shared__ int tmp[256];
  int v = (threadIdx.x < NB_SCAN) ? bsums[threadIdx.x] : 0;
  tmp[threadIdx.x] = v;
  __syncthreads();
#pragma unroll
  for (int d = 1; d < 256; d <<= 1) {
    int t = (threadIdx.x >= d) ? tmp[threadIdx.x - d] : 0;
    __syncthreads();
    tmp[threadIdx.x] += t;
    __syncthreads();
  }
  bpre[threadIdx.x] = tmp[threadIdx.x] - v;       // exclusive block prefix
}

__global__ __launch_bounds__(256)
void scan3(int* __restrict__ offs, const int* __restrict__ bpre) {
  int i = blockIdx.x * 256 + threadIdx.x;
  offs[i] += bpre[blockIdx.x];
}

__global__ __launch_bounds__(256)
void scatter_k(const int* __restrict__ ei, int* __restrict__ offs,
               int* __restrict__ sorted) {
  int e = blockIdx.x * 256 + threadIdx.x;
  if (e >= N_EDGES) return;
  int d = ei[N_EDGES + e];
  int pos = atomicAdd(&offs[d], 1);
  sorted[pos] = e;
}

// ---------------------------------------------------------------------------
// Edge MLP — block-cooperative, 64 dst-sorted edges / block.
// R6: sA/sH unioned into one buffer (sA dead after GEMM1; +1 barrier) ->
// LDS 52224 B -> 3 blocks/CU (was 55808 -> 2). Fast silu (rcp, no IEEE div).
// ---------------------------------------------------------------------------
#define LDA_E 168   // 160 + 8 pad shorts; row = 336 B (16B aligned, 21x16B odd)
#define LDH   264   // 256 + 8 pad shorts; row = 528 B (16B aligned, 33x16B odd)
#define LDC   68    // fp32 stride of C tile

__global__ __launch_bounds__(256, 2)
void edge_mlp(const float* __restrict__ h, const float* __restrict__ ea,
              const int* __restrict__ ei, const int* __restrict__ sorted,
              const short* __restrict__ w1f, const float* __restrict__ b1,
              const short* __restrict__ w2f, const float* __restrict__ b2,
              float* __restrict__ agg) {
  __shared__ __align__(16) short buf[64 * LDH];    // sA [64][LDA_E] then sH [64][LDH]
  __shared__ __align__(16) float sC[64 * LDC];     // 17408 B
  __shared__ int s_ids[4][32];                     // per-wave src[16], dst[16]

  const int tid  = threadIdx.x;
  const int lane = tid & 63;
  const int wave = tid >> 6;
  const int col  = lane & 15;
  const int quad = lane >> 4;
  const int eb   = blockIdx.x * 64 + wave * 16;    // this wave's 16 sorted slots
  short* sA = buf;
  short* sH = buf;

  // ---- resolve sorted edge ids -> src/dst (wave-local; read by same wave)
  if (lane < 32) {
    int e0 = sorted[eb + (lane & 15)];
    s_ids[wave][lane] = (lane < 16) ? ei[e0] : ei[N_EDGES + e0];
  }

  // ---- stage: each wave its 16 edges x 160 fp32 (40 float4/edge) -> bf16
#pragma unroll
  for (int it = 0; it < 10; ++it) {
    int idx = it * 64 + lane;       // 0..639
    int e   = idx / 40;
    int j   = idx - e * 40;
    int k   = j * 4;
    float4v v;
    if (k < 64) {
      int d = s_ids[wave][16 + e];
      v = *(const float4v*)(h + (size_t)d * D_MODEL + k);
    } else if (k < 128) {
      int s = s_ids[wave][e];
      v = *(const float4v*)(h + (size_t)s * D_MODEL + (k - 64));
    } else {
      int e0 = sorted[eb + e];
      v = *(const float4v*)(ea + (size_t)e0 * 32 + (k - 128));
    }
    short* p = &sA[(wave * 16 + e) * LDA_E + k];
    p[0] = f2bf(v.x); p[1] = f2bf(v.y); p[2] = f2bf(v.z); p[3] = f2bf(v.w);
  }
  __syncthreads();                                  // b1: sA visible

  // ---- GEMM1: [64,160] x [160,256]; wave covers n-tiles [4w, 4w+4)
  f32x4 acc[4][4];
#pragma unroll
  for (int mt = 0; mt < 4; ++mt)
#pragma unroll
    for (int nt = 0; nt < 4; ++nt)
      acc[mt][nt] = (f32x4){0.f, 0.f, 0.f, 0.f};

  short8 bf[2][4];
#pragma unroll
  for (int nt = 0; nt < 4; ++nt)
    bf[0][nt] = *(const short8*)(w1f + (size_t)((wave * 4 + nt) * 64 + lane) * 8);

#pragma unroll
  for (int kt = 0; kt < 5; ++kt) {
    if (kt < 4) {
#pragma unroll
      for (int nt = 0; nt < 4; ++nt)
        bf[(kt + 1) & 1][nt] = *(const short8*)(
            w1f + (size_t)(((kt + 1) * 16 + wave * 4 + nt) * 64 + lane) * 8);
    }
    short8 af[4];
#pragma unroll
    for (int mt = 0; mt < 4; ++mt)
      af[mt] = *(const short8*)&sA[(mt * 16 + col) * LDA_E + kt * 32 + quad * 8];
#pragma unroll
    for (int nt = 0; nt < 4; ++nt)
#pragma unroll
      for (int mt = 0; mt < 4; ++mt)
        acc[mt][nt] = mfma16(af[mt], bf[kt & 1][nt], acc[mt][nt]);
  }
  __syncthreads();                                  // b2: sA dead, safe to reuse

  // ---- bias + silu -> sH (wave writes its 64-col slice, all 64 rows)
#pragma unroll
  for (int nt = 0; nt < 4; ++nt) {
    const int n = (wave * 4 + nt) * 16 + col;
    const float bias = b1[n];
#pragma unroll
    for (int mt = 0; mt < 4; ++mt) {
#pragma unroll
      for (int r = 0; r < 4; ++r) {
        const int row = mt * 16 + quad * 4 + r;
        sH[row * LDH + n] = f2bf(silu_f(acc[mt][nt][r] + bias));
      }
    }
  }
  __syncthreads();                                  // b3: sH visible

  // ---- GEMM2: [64,256] x [256,64]; wave covers n-tile `wave` (16 cols)
  f32x4 acc2[4];
#pragma unroll
  for (int mt = 0; mt < 4; ++mt) acc2[mt] = (f32x4){0.f, 0.f, 0.f, 0.f};

  short8 bf2[2];
  bf2[0] = *(const short8*)(w2f + (size_t)(wave * 64 + lane) * 8);

#pragma unroll
  for (int kt = 0; kt < 8; ++kt) {
    if (kt < 7)
      bf2[(kt + 1) & 1] = *(const short8*)(
          w2f + (size_t)(((kt + 1) * 4 + wave) * 64 + lane) * 8);
    short8 af[4];
#pragma unroll
    for (int mt = 0; mt < 4; ++mt)
      af[mt] = *(const short8*)&sH[(mt * 16 + col) * LDH + kt * 32 + quad * 8];
#pragma unroll
    for (int mt = 0; mt < 4; ++mt)
      acc2[mt] = mfma16(af[mt], bf2[kt & 1], acc2[mt]);
  }

  // ---- dump C (+bias) into separate sC tile (no barrier needed before)
  {
    const int n = wave * 16 + col;
    const float bias = b2[n];
#pragma unroll
    for (int mt = 0; mt < 4; ++mt)
#pragma unroll
      for (int r = 0; r < 4; ++r)
        sC[(mt * 16 + quad * 4 + r) * LDC + n] = acc2[mt][r] + bias;
  }
  __syncthreads();                                  // b4: sC visible

  // ---- run-reduce own 16 rows (dst-sorted): one atomic per run per feature
  float sum = 0.f;
  int prev = s_ids[wave][16];
#pragma unroll
  for (int r = 0; r < 16; ++r) {
    float v = sC[(wave * 16 + r) * LDC + lane];
    int d = s_ids[wave][16 + r];          // LDS broadcast -> wave-uniform
    if (d != prev) {
      atomicAdd(agg + (size_t)prev * D_MODEL + lane, sum);
      sum = 0.f; prev = d;
    }
    sum += v;
  }
  atomicAdd(agg + (size_t)prev * D_MODEL + lane, sum);
}

// ---------------------------------------------------------------------------
// Node MLP — block-cooperative, 64 nodes / block, sA/sH unioned.
// R6: GraphNorm stats (s1,s2,cnt) fused into the epilogue: each lane's 16
// rows are an ascending subsequence of the sorted batch -> per-lane
// run-reduce; counts via ballot run-length scan in wave 3.
// ---------------------------------------------------------------------------
#define LDA_N 136   // 128 + 8 pad shorts; row = 272 B (16B aligned, 17x16B odd)

__global__ __launch_bounds__(256, 2)
void node_mlp(const float* __restrict__ h, const float* __restrict__ agg,
              const short* __restrict__ w1f, const float* __restrict__ b1,
              const short* __restrict__ w2f, const float* __restrict__ b2,
              const int* __restrict__ batch,
              float* __restrict__ hnew,
              float* __restrict__ s1, float* __restrict__ s2,
              float* __restrict__ cnt) {
  __shared__ __align__(16) short buf[64 * LDH];    // sA [64][LDA_N] then sH
  __shared__ int s_b[64];                          // batch ids of block rows

  const int tid  = threadIdx.x;
  const int lane = tid & 63;
  const int wave = tid >> 6;
  const int col  = lane & 15;
  const int quad = lane >> 4;
  const int nb   = blockIdx.x * 64;
  short* sA = buf;
  short* sH = buf;

  if (tid < 64) {
    int gi = nb + tid;
    s_b[tid] = batch[(gi < N_NODES) ? gi : (N_NODES - 1)];
  }

  // ---- stage: each wave its 16 nodes x 128 fp32 (32 float4/node)
#pragma unroll
  for (int it = 0; it < 8; ++it) {
    int idx = it * 64 + lane;     // 0..511
    int i   = idx >> 5;           // 0..15
    int j   = idx & 31;
    int k   = j * 4;
    int row = wave * 16 + i;
    int gi  = nb + row;
    if (gi >= N_NODES) gi = N_NODES - 1;   // clamp; OOB rows never stored
    float4v v = (k < 64) ? *(const float4v*)(h + (size_t)gi * D_MODEL + k)
                         : *(const float4v*)(agg + (size_t)gi * D_MODEL + (k - 64));
    short* p = &sA[row * LDA_N + k];
    p[0] = f2bf(v.x); p[1] = f2bf(v.y); p[2] = f2bf(v.z); p[3] = f2bf(v.w);
  }
  __syncthreads();                                  // b1

  // ---- per-graph node counts (one wave; ballot run-length over 64 rows)
  if (wave == 3) {
    int gi = nb + lane;
    bool valid = gi < N_NODES;
    int g = s_b[lane];
    int gp = __shfl_up(g, 1);
    bool start = valid && (lane == 0 || g != gp);
    unsigned long long bmask = __ballot(start);
    unsigned long long imask = __ballot(!valid);
    if (start) {
      unsigned long long higher =
          (lane == 63) ? 0ULL : (((bmask | imask) >> (lane + 1)) << (lane + 1));
      int next = higher ? (__ffsll((long long)higher) - 1) : 64;
      atomicAdd(&cnt[g], (float)(next - lane));
    }
  }

  // ---- GEMM1: K=128; wave covers n-tiles [4w, 4w+4)
  f32x4 acc[4][4];
#pragma unroll
  for (int mt = 0; mt < 4; ++mt)
#pragma unroll
    for (int nt = 0; nt < 4; ++nt)
      acc[mt][nt] = (f32x4){0.f, 0.f, 0.f, 0.f};

  short8 bf[2][4];
#pragma unroll
  for (int nt = 0; nt < 4; ++nt)
    bf[0][nt] = *(const short8*)(w1f + (size_t)((wave * 4 + nt) * 64 + lane) * 8);

#pragma unroll
  for (int kt = 0; kt < 4; ++kt) {
    if (kt < 3) {
#pragma unroll
      for (int nt = 0; nt < 4; ++nt)
        bf[(kt + 1) & 1][nt] = *(const short8*)(
            w1f + (size_t)(((kt + 1) * 16 + wave * 4 + nt) * 64 + lane) * 8);
    }
    short8 af[4];
#pragma unroll
    for (int mt = 0; mt < 4; ++mt)
      af[mt] = *(const short8*)&sA[(mt * 16 + col) * LDA_N + kt * 32 + quad * 8];
#pragma unroll
    for (int nt = 0; nt < 4; ++nt)
#pragma unroll
      for (int mt = 0; mt < 4; ++mt)
        acc[mt][nt] = mfma16(af[mt], bf[kt & 1][nt], acc[mt][nt]);
  }
  __syncthreads();                                  // b2: sA dead

#pragma unroll
  for (int nt = 0; nt < 4; ++nt) {
    const int n = (wave * 4 + nt) * 16 + col;
    const float bias = b1[n];
#pragma unroll
    for (int mt = 0; mt < 4; ++mt) {
#pragma unroll
      for (int r = 0; r < 4; ++r) {
        const int row = mt * 16 + quad * 4 + r;
        sH[row * LDH + n] = f2bf(silu_f(acc[mt][nt][r] + bias));
      }
    }
  }
  __syncthreads();                                  // b3: sH visible

  // ---- GEMM2: K=256; wave covers n-tile `wave`
  f32x4 acc2[4];
#pragma unroll
  for (int mt = 0; mt < 4; ++mt) acc2[mt] = (f32x4){0.f, 0.f, 0.f, 0.f};

  short8 bf2[2];
  bf2[0] = *(const short8*)(w2f + (size_t)(wave * 64 + lane) * 8);

#pragma unroll
  for (int kt = 0; kt < 8; ++kt) {
    if (kt < 7)
      bf2[(kt + 1) & 1] = *(const short8*)(
          w2f + (size_t)(((kt + 1) * 4 + wave) * 64 + lane) * 8);
    short8 af[4];
#pragma unroll
    for (int mt = 0; mt < 4; ++mt)
      af[mt] = *(const short8*)&sH[(mt * 16 + col) * LDH + kt * 32 + quad * 8];
#pragma unroll
    for (int mt = 0; mt < 4; ++mt)
      acc2[mt] = mfma16(af[mt], bf2[kt & 1], acc2[mt]);
  }

  // ---- epilogue: h_new = h + dh -> global, fused per-lane run-reduce of
  // s1/s2 over this lane's 16 ascending rows of the sorted batch.
  {
    const int n = wave * 16 + col;
    const float bias = b2[n];
    float a1 = 0.f, a2 = 0.f;
    int prev = s_b[quad * 4];     // lane's first row (mt=0, r=0)
#pragma unroll
    for (int mt = 0; mt < 4; ++mt) {
#pragma unroll
      for (int r = 0; r < 4; ++r) {
        const int row = mt * 16 + quad * 4 + r;
        const int gi = nb + row;
        const bool valid = gi < N_NODES;
        int g = s_b[row];
        if (g != prev) {
          atomicAdd(&s1[prev * D_MODEL + n], a1);
          atomicAdd(&s2[prev * D_MODEL + n], a2);
          a1 = 0.f; a2 = 0.f; prev = g;
        }
        if (valid) {
          float hv = h[(size_t)gi * D_MODEL + n] + acc2[mt][r] + bias;
          hnew[(size_t)gi * D_MODEL + n] = hv;
          a1 += hv; a2 += hv * hv;
        }
      }
    }
    atomicAdd(&s1[prev * D_MODEL + n], a1);
    atomicAdd(&s2[prev * D_MODEL + n], a2);
  }
}

// ---------------------------------------------------------------------------
// GraphNorm normalize (stats already produced by node_mlp).
// var(x - a*m) = E[x^2] - 2*a*m^2 + a^2*m^2,  m = s1/c.
// ---------------------------------------------------------------------------
__global__ __launch_bounds__(256)
void gn_norm(float* __restrict__ x, const int* __restrict__ batch,
             const float* __restrict__ s1, const float* __restrict__ s2,
             const float* __restrict__ cnt, const float* __restrict__ alpha,
             const float* __restrict__ weight, const float* __restrict__ bias) {
  int idx = blockIdx.x * 256 + threadIdx.x;
  if (idx >= N_NODES * D_MODEL) return;
  int i = idx >> 6, f = idx & 63;
  int g = batch[i];
  float c = fmaxf(cnt[g], 1.f);
  float m   = s1[g * D_MODEL + f] / c;
  float ex2 = s2[g * D_MODEL + f] / c;
  float a = alpha[f];
  float var = ex2 - 2.f * a * m * m + a * a * m * m;
  float hc = x[idx] - a * m;
  x[idx] = weight[f] * hc * rsqrtf(var + EPS_GN) + bias[f];
}

// ---------------------------------------------------------------------------
extern "C" void kernel_launch(void* const* d_in, const int* in_sizes, int n_in,
                              void* d_out, int out_size, void* d_ws, size_t ws_size,
                              hipStream_t stream) {
  const float* h     = (const float*)d_in[0];
  const float* ea    = (const float*)d_in[1];
  const int*   ei    = (const int*)d_in[2];   // [2][E], row0=src, row1=dst
  const int*   batch = (const int*)d_in[3];
  const float* mw1   = (const float*)d_in[4];
  const float* mb1   = (const float*)d_in[5];
  const float* mw2   = (const float*)d_in[6];
  const float* mb2   = (const float*)d_in[7];
  const float* uw1   = (const float*)d_in[8];
  const float* ub1   = (const float*)d_in[9];
  const float* uw2   = (const float*)d_in[10];
  const float* ub2   = (const float*)d_in[11];
  const float* gw    = (const float*)d_in[12];
  const float* gb    = (const float*)d_in[13];
  const float* ga    = (const float*)d_in[14];

  char* ws = (char*)d_ws;
  float* agg    = (float*)(ws + 0);             // 12,800,000 B
  short* w1f    = (short*)(ws + 12800000);      //     81,920 B
  short* w2f    = (short*)(ws + 12881920);      //     32,768 B
  short* u1f    = (short*)(ws + 12914688);      //     65,536 B
  short* u2f    = (short*)(ws + 12980224);      //     32,768 B
  float* s1     = (float*)(ws + 13012992);      //     16,384 B
  float* s2     = (float*)(ws + 13029376);      //     16,384 B
  float* cnt    = (float*)(ws + 13045760);      //        256 B
  int*   hist   = (int*)  (ws + 13046016);      //    200,704 B (50176 ints)
  int*   offs   = (int*)  (ws + 13246720);      //    200,704 B
  int*   bsums  = (int*)  (ws + 13447424);      //      1,024 B
  int*   bpre   = (int*)  (ws + 13448448);      //      1,024 B
  int*   sorted = (int*)  (ws + 13449472);      //  3,200,000 B  -> end 16,649,472

  hipMemsetAsync(agg, 0, 12800000, stream);
  hipMemsetAsync(ws + 13012992, 0, 33024, stream);   // s1, s2, cnt
  hipMemsetAsync(hist, 0, 200704, stream);

  prep_all<<<52, 256, 0, stream>>>(mw1, mw2, uw1, uw2, w1f, w2f, u1f, u2f);

  // counting sort of edges by dst
  hist_k  <<<(N_EDGES + 255) / 256, 256, 0, stream>>>(ei, hist);
  scan1   <<<NB_SCAN, 256, 0, stream>>>(hist, offs, bsums);
  scan2   <<<1, 256, 0, stream>>>(bsums, bpre);
  scan3   <<<NB_SCAN, 256, 0, stream>>>(offs, bpre);
  scatter_k<<<(N_EDGES + 255) / 256, 256, 0, stream>>>(ei, offs, sorted);

  edge_mlp<<<N_EDGES / 64, 256, 0, stream>>>(h, ea, ei, sorted,
                                             w1f, mb1, w2f, mb2, agg);

  node_mlp<<<(N_NODES + 63) / 64, 256, 0, stream>>>(h, agg, u1f, ub1, u2f, ub2,
                                                    batch, (float*)d_out,
                                                    s1, s2, cnt);

  gn_norm<<<(N_NODES * D_MODEL + 255) / 256, 256, 0, stream>>>(
      (float*)d_out, batch, s1, s2, cnt, ga, gw, gb);
}

// Round 7
// 456.325 us; speedup vs baseline: 1.8724x; 1.2582x over previous
//
#include <hip/hip_runtime.h>
#include <hip/hip_bf16.h>
#include <stdint.h>

#define N_NODES   50000
#define N_EDGES   800000
#define D_MODEL   64
#define D_HIDDEN  256
#define N_GRAPHS  64
#define EPS_GN    1e-5f

#define NBINS_PAD 50176            // 196 * 256, zero-padded histogram
#define NB_SCAN   196

typedef __attribute__((ext_vector_type(8))) short short8;   // 8 bf16 (4 VGPRs)
typedef __attribute__((ext_vector_type(4))) float f32x4;
typedef __attribute__((ext_vector_type(4))) float float4v;
typedef __attribute__((ext_vector_type(2))) unsigned int uint2v;
typedef __attribute__((ext_vector_type(4))) unsigned int uint4v;

static __device__ __forceinline__ short f2bf(float f) {
  union { float f; uint32_t u; } v; v.f = f;
  uint32_t r = (v.u + 0x7fffu + ((v.u >> 16) & 1u)) >> 16;   // RNE
  return (short)(uint16_t)r;
}

// pack two fp32 -> bf16x2 (RNE), hi16 extraction fused via v_perm_b32
static __device__ __forceinline__ uint32_t pack_bf16x2(float lo, float hi) {
  union { float f; uint32_t u; } a, b;
  a.f = lo; b.f = hi;
  uint32_t ra = a.u + 0x7fffu + ((a.u >> 16) & 1u);
  uint32_t rb = b.u + 0x7fffu + ((b.u >> 16) & 1u);
  return __builtin_amdgcn_perm(rb, ra, 0x07060302u);  // {rb.b3,rb.b2,ra.b3,ra.b2}
}

// fast silu: hardware rcp (rel err ~2^-22 << bf16 rounding) instead of IEEE div
static __device__ __forceinline__ float silu_f(float x) {
  return x * __builtin_amdgcn_rcpf(1.0f + __expf(-x));
}

static __device__ __forceinline__ f32x4 mfma16(short8 a, short8 b, f32x4 c) {
  return __builtin_amdgcn_mfma_f32_16x16x32_bf16(a, b, c, 0, 0, 0);
}

// ---------------------------------------------------------------------------
// Weight prep (4 mats -> MFMA B-frag layout) + h -> bf16 row-major copy.
// B-frag: [kt][nt][lane][8]; elem j of lane L = w[kt*32+(L>>4)*8+j][nt*16+(L&15)]
// ---------------------------------------------------------------------------
#define HBF_BLOCKS 1563   // ceil(50000*64/8/256)

__global__ void prep_all(const float* __restrict__ mw1, const float* __restrict__ mw2,
                         const float* __restrict__ uw1, const float* __restrict__ uw2,
                         const float* __restrict__ h,
                         short* __restrict__ w1f, short* __restrict__ w2f,
                         short* __restrict__ u1f, short* __restrict__ u2f,
                         short* __restrict__ h_bf) {
  int b = blockIdx.x;
  if (b >= 52) {                       // h -> bf16, 8 elems/thread
    int t2 = (b - 52) * 256 + threadIdx.x;
    if (t2 < N_NODES * D_MODEL / 8) {
      const float4v* src = (const float4v*)(h + (size_t)t2 * 8);
      float4v v0 = src[0], v1 = src[1];
      uint4v p = {pack_bf16x2(v0.x, v0.y), pack_bf16x2(v0.z, v0.w),
                  pack_bf16x2(v1.x, v1.y), pack_bf16x2(v1.z, v1.w)};
      *(uint4v*)(h_bf + (size_t)t2 * 8) = p;
    }
    return;
  }
  const float* w; short* out; int K, Nn, t;
  if (b < 20)      { w = mw1; out = w1f; K = 160; Nn = 256; t = b * 256 + threadIdx.x; }
  else if (b < 28) { w = mw2; out = w2f; K = 256; Nn = 64;  t = (b - 20) * 256 + threadIdx.x; }
  else if (b < 44) { w = uw1; out = u1f; K = 128; Nn = 256; t = (b - 28) * 256 + threadIdx.x; }
  else             { w = uw2; out = u2f; K = 256; Nn = 64;  t = (b - 44) * 256 + threadIdx.x; }
  int total = (K >> 5) * (Nn >> 4) * 64;
  if (t >= total) return;
  int lane = t & 63;
  int rest = t >> 6;
  int ntN = Nn >> 4;
  int nt = rest % ntN;
  int kt = rest / ntN;
  int n  = nt * 16 + (lane & 15);
  int k0 = kt * 32 + (lane >> 4) * 8;
  short* o = out + (size_t)t * 8;
#pragma unroll
  for (int j = 0; j < 8; ++j)
    o[j] = f2bf(w[(size_t)(k0 + j) * Nn + n]);
}

// ---------------------------------------------------------------------------
// Counting sort of edges by dst: hist -> 2-level exclusive scan -> scatter.
// ---------------------------------------------------------------------------
__global__ __launch_bounds__(256)
void hist_k(const int* __restrict__ ei, int* __restrict__ hist) {
  int e = blockIdx.x * 256 + threadIdx.x;
  if (e >= N_EDGES) return;
  atomicAdd(&hist[ei[N_EDGES + e]], 1);
}

__global__ __launch_bounds__(256)
void scan1(const int* __restrict__ hist, int* __restrict__ offs,
           int* __restrict__ bsums) {
  __shared__ int tmp[256];
  int i = blockIdx.x * 256 + threadIdx.x;
  int v = hist[i];
  tmp[threadIdx.x] = v;
  __syncthreads();
#pragma unroll
  for (int d = 1; d < 256; d <<= 1) {
    int t = (threadIdx.x >= d) ? tmp[threadIdx.x - d] : 0;
    __syncthreads();
    tmp[threadIdx.x] += t;
    __syncthreads();
  }
  offs[i] = tmp[threadIdx.x] - v;                 // exclusive within block
  if (threadIdx.x == 255) bsums[blockIdx.x] = tmp[255];
}

__global__ __launch_bounds__(256)
void scan2(const int* __restrict__ bsums, int* __restrict__ bpre) {
  __shared__ int tmp[256];
  int v = (threadIdx.x < NB_SCAN) ? bsums[threadIdx.x] : 0;
  tmp[threadIdx.x] = v;
  __syncthreads();
#pragma unroll
  for (int d = 1; d < 256; d <<= 1) {
    int t = (threadIdx.x >= d) ? tmp[threadIdx.x - d] : 0;
    __syncthreads();
    tmp[threadIdx.x] += t;
    __syncthreads();
  }
  bpre[threadIdx.x] = tmp[threadIdx.x] - v;       // exclusive block prefix
}

__global__ __launch_bounds__(256)
void scan3(int* __restrict__ offs, const int* __restrict__ bpre) {
  int i = blockIdx.x * 256 + threadIdx.x;
  offs[i] += bpre[blockIdx.x];
}

__global__ __launch_bounds__(256)
void scatter_k(const int* __restrict__ ei, int* __restrict__ offs,
               int* __restrict__ sorted) {
  int e = blockIdx.x * 256 + threadIdx.x;
  if (e >= N_EDGES) return;
  int d = ei[N_EDGES + e];
  int pos = atomicAdd(&offs[d], 1);
  sorted[pos] = e;
}

// ---------------------------------------------------------------------------
// Edge MLP — block-cooperative, 64 dst-sorted edges / block.
// R7: h pre-converted to bf16 (staging = pure short8 copy for 128/160 cols;
// h gather bytes halved); edge_attr cvt via v_perm packed bf16; ids cached.
// ---------------------------------------------------------------------------
#define LDA_E 168   // 160 + 8 pad shorts; row = 336 B (16B aligned)
#define LDH   264   // 256 + 8 pad shorts; row = 528 B (16B aligned)
#define LDC   68    // fp32 stride of C tile

__global__ __launch_bounds__(256, 2)
void edge_mlp(const short* __restrict__ h_bf, const float* __restrict__ ea,
              const int* __restrict__ ei, const int* __restrict__ sorted,
              const short* __restrict__ w1f, const float* __restrict__ b1,
              const short* __restrict__ w2f, const float* __restrict__ b2,
              float* __restrict__ agg) {
  __shared__ __align__(16) short buf[64 * LDH];    // sA [64][LDA_E] then sH
  __shared__ __align__(16) float sC[64 * LDC];     // 17408 B
  __shared__ int s_ids[4][48];                     // src[16], dst[16], eid[16]

  const int tid  = threadIdx.x;
  const int lane = tid & 63;
  const int wave = tid >> 6;
  const int col  = lane & 15;
  const int quad = lane >> 4;
  const int eb   = blockIdx.x * 64 + wave * 16;    // this wave's 16 sorted slots
  short* sA = buf;
  short* sH = buf;

  // ---- resolve sorted edge ids -> src/dst/eid (wave-local)
  if (lane < 48) {
    int i15 = lane & 15;
    int e0 = sorted[eb + i15];
    int v;
    if (lane < 16)      v = ei[e0];
    else if (lane < 32) v = ei[N_EDGES + e0];
    else                v = e0;
    s_ids[wave][lane] = v;
  }

  // ---- stage h_dst | h_src rows (bf16 copy, no conversion)
#pragma unroll
  for (int it = 0; it < 2; ++it) {
    int idx = it * 64 + lane;        // 0..127
    int e = idx >> 3, c = idx & 7;
    int row = wave * 16 + e;
    int d = s_ids[wave][16 + e];
    int s = s_ids[wave][e];
    *(short8*)&sA[row * LDA_E + c * 8] =
        *(const short8*)(h_bf + (size_t)d * D_MODEL + c * 8);
    *(short8*)&sA[row * LDA_E + 64 + c * 8] =
        *(const short8*)(h_bf + (size_t)s * D_MODEL + c * 8);
  }
  // ---- stage edge_attr (fp32 -> packed bf16)
#pragma unroll
  for (int it = 0; it < 2; ++it) {
    int idx = it * 64 + lane;        // 0..127
    int e = idx >> 3, j = idx & 7;
    int row = wave * 16 + e;
    int eid = s_ids[wave][32 + e];
    float4v v = *(const float4v*)(ea + (size_t)eid * 32 + j * 4);
    uint2v p = {pack_bf16x2(v.x, v.y), pack_bf16x2(v.z, v.w)};
    *(uint2v*)&sA[row * LDA_E + 128 + j * 4] = p;
  }
  __syncthreads();                                  // b1: sA visible

  // ---- GEMM1: [64,160] x [160,256]; wave covers n-tiles [4w, 4w+4)
  f32x4 acc[4][4];
#pragma unroll
  for (int mt = 0; mt < 4; ++mt)
#pragma unroll
    for (int nt = 0; nt < 4; ++nt)
      acc[mt][nt] = (f32x4){0.f, 0.f, 0.f, 0.f};

  short8 bf[2][4];
#pragma unroll
  for (int nt = 0; nt < 4; ++nt)
    bf[0][nt] = *(const short8*)(w1f + (size_t)((wave * 4 + nt) * 64 + lane) * 8);

#pragma unroll
  for (int kt = 0; kt < 5; ++kt) {
    if (kt < 4) {
#pragma unroll
      for (int nt = 0; nt < 4; ++nt)
        bf[(kt + 1) & 1][nt] = *(const short8*)(
            w1f + (size_t)(((kt + 1) * 16 + wave * 4 + nt) * 64 + lane) * 8);
    }
    short8 af[4];
#pragma unroll
    for (int mt = 0; mt < 4; ++mt)
      af[mt] = *(const short8*)&sA[(mt * 16 + col) * LDA_E + kt * 32 + quad * 8];
#pragma unroll
    for (int nt = 0; nt < 4; ++nt)
#pragma unroll
      for (int mt = 0; mt < 4; ++mt)
        acc[mt][nt] = mfma16(af[mt], bf[kt & 1][nt], acc[mt][nt]);
  }
  __syncthreads();                                  // b2: sA dead, safe to reuse

  // ---- bias + silu -> sH (wave writes its 64-col slice, all 64 rows)
#pragma unroll
  for (int nt = 0; nt < 4; ++nt) {
    const int n = (wave * 4 + nt) * 16 + col;
    const float bias = b1[n];
#pragma unroll
    for (int mt = 0; mt < 4; ++mt) {
#pragma unroll
      for (int r = 0; r < 4; ++r) {
        const int row = mt * 16 + quad * 4 + r;
        sH[row * LDH + n] = f2bf(silu_f(acc[mt][nt][r] + bias));
      }
    }
  }
  __syncthreads();                                  // b3: sH visible

  // ---- GEMM2: [64,256] x [256,64]; wave covers n-tile `wave` (16 cols)
  f32x4 acc2[4];
#pragma unroll
  for (int mt = 0; mt < 4; ++mt) acc2[mt] = (f32x4){0.f, 0.f, 0.f, 0.f};

  short8 bf2[2];
  bf2[0] = *(const short8*)(w2f + (size_t)(wave * 64 + lane) * 8);

#pragma unroll
  for (int kt = 0; kt < 8; ++kt) {
    if (kt < 7)
      bf2[(kt + 1) & 1] = *(const short8*)(
          w2f + (size_t)(((kt + 1) * 4 + wave) * 64 + lane) * 8);
    short8 af[4];
#pragma unroll
    for (int mt = 0; mt < 4; ++mt)
      af[mt] = *(const short8*)&sH[(mt * 16 + col) * LDH + kt * 32 + quad * 8];
#pragma unroll
    for (int mt = 0; mt < 4; ++mt)
      acc2[mt] = mfma16(af[mt], bf2[kt & 1], acc2[mt]);
  }

  // ---- dump C (+bias) into separate sC tile
  {
    const int n = wave * 16 + col;
    const float bias = b2[n];
#pragma unroll
    for (int mt = 0; mt < 4; ++mt)
#pragma unroll
      for (int r = 0; r < 4; ++r)
        sC[(mt * 16 + quad * 4 + r) * LDC + n] = acc2[mt][r] + bias;
  }
  __syncthreads();                                  // b4: sC visible

  // ---- run-reduce own 16 rows (dst-sorted): one atomic per run per feature
  float sum = 0.f;
  int prev = s_ids[wave][16];
#pragma unroll
  for (int r = 0; r < 16; ++r) {
    float v = sC[(wave * 16 + r) * LDC + lane];
    int d = s_ids[wave][16 + r];          // LDS broadcast -> wave-uniform
    if (d != prev) {
      atomicAdd(agg + (size_t)prev * D_MODEL + lane, sum);
      sum = 0.f; prev = d;
    }
    sum += v;
  }
  atomicAdd(agg + (size_t)prev * D_MODEL + lane, sum);
}

// ---------------------------------------------------------------------------
// Node MLP — block-cooperative, 64 nodes / block, fused GraphNorm stats.
// R7: h part staged from h_bf (copy); agg cvt via packed bf16.
// ---------------------------------------------------------------------------
#define LDA_N 136   // 128 + 8 pad shorts; row = 272 B (16B aligned)

__global__ __launch_bounds__(256, 2)
void node_mlp(const float* __restrict__ h, const short* __restrict__ h_bf,
              const float* __restrict__ agg,
              const short* __restrict__ w1f, const float* __restrict__ b1,
              const short* __restrict__ w2f, const float* __restrict__ b2,
              const int* __restrict__ batch,
              float* __restrict__ hnew,
              float* __restrict__ s1, float* __restrict__ s2,
              float* __restrict__ cnt) {
  __shared__ __align__(16) short buf[64 * LDH];    // sA [64][LDA_N] then sH
  __shared__ int s_b[64];                          // batch ids of block rows

  const int tid  = threadIdx.x;
  const int lane = tid & 63;
  const int wave = tid >> 6;
  const int col  = lane & 15;
  const int quad = lane >> 4;
  const int nb   = blockIdx.x * 64;
  short* sA = buf;
  short* sH = buf;

  if (tid < 64) {
    int gi = nb + tid;
    s_b[tid] = batch[(gi < N_NODES) ? gi : (N_NODES - 1)];
  }

  // ---- stage h rows (bf16 copy)
#pragma unroll
  for (int it = 0; it < 2; ++it) {
    int idx = it * 64 + lane;     // 0..127
    int i = idx >> 3, c = idx & 7;
    int row = wave * 16 + i;
    int gi = nb + row;
    if (gi >= N_NODES) gi = N_NODES - 1;
    *(short8*)&sA[row * LDA_N + c * 8] =
        *(const short8*)(h_bf + (size_t)gi * D_MODEL + c * 8);
  }
  // ---- stage agg rows (fp32 -> packed bf16)
#pragma unroll
  for (int it = 0; it < 4; ++it) {
    int idx = it * 64 + lane;     // 0..255
    int i = idx >> 4, j = idx & 15;
    int row = wave * 16 + i;
    int gi = nb + row;
    if (gi >= N_NODES) gi = N_NODES - 1;
    float4v v = *(const float4v*)(agg + (size_t)gi * D_MODEL + j * 4);
    uint2v p = {pack_bf16x2(v.x, v.y), pack_bf16x2(v.z, v.w)};
    *(uint2v*)&sA[row * LDA_N + 64 + j * 4] = p;
  }
  __syncthreads();                                  // b1

  // ---- per-graph node counts (one wave; ballot run-length over 64 rows)
  if (wave == 3) {
    int gi = nb + lane;
    bool valid = gi < N_NODES;
    int g = s_b[lane];
    int gp = __shfl_up(g, 1);
    bool start = valid && (lane == 0 || g != gp);
    unsigned long long bmask = __ballot(start);
    unsigned long long imask = __ballot(!valid);
    if (start) {
      unsigned long long higher =
          (lane == 63) ? 0ULL : (((bmask | imask) >> (lane + 1)) << (lane + 1));
      int next = higher ? (__ffsll((long long)higher) - 1) : 64;
      atomicAdd(&cnt[g], (float)(next - lane));
    }
  }

  // ---- GEMM1: K=128; wave covers n-tiles [4w, 4w+4)
  f32x4 acc[4][4];
#pragma unroll
  for (int mt = 0; mt < 4; ++mt)
#pragma unroll
    for (int nt = 0; nt < 4; ++nt)
      acc[mt][nt] = (f32x4){0.f, 0.f, 0.f, 0.f};

  short8 bf[2][4];
#pragma unroll
  for (int nt = 0; nt < 4; ++nt)
    bf[0][nt] = *(const short8*)(w1f + (size_t)((wave * 4 + nt) * 64 + lane) * 8);

#pragma unroll
  for (int kt = 0; kt < 4; ++kt) {
    if (kt < 3) {
#pragma unroll
      for (int nt = 0; nt < 4; ++nt)
        bf[(kt + 1) & 1][nt] = *(const short8*)(
            w1f + (size_t)(((kt + 1) * 16 + wave * 4 + nt) * 64 + lane) * 8);
    }
    short8 af[4];
#pragma unroll
    for (int mt = 0; mt < 4; ++mt)
      af[mt] = *(const short8*)&sA[(mt * 16 + col) * LDA_N + kt * 32 + quad * 8];
#pragma unroll
    for (int nt = 0; nt < 4; ++nt)
#pragma unroll
      for (int mt = 0; mt < 4; ++mt)
        acc[mt][nt] = mfma16(af[mt], bf[kt & 1][nt], acc[mt][nt]);
  }
  __syncthreads();                                  // b2: sA dead

#pragma unroll
  for (int nt = 0; nt < 4; ++nt) {
    const int n = (wave * 4 + nt) * 16 + col;
    const float bias = b1[n];
#pragma unroll
    for (int mt = 0; mt < 4; ++mt) {
#pragma unroll
      for (int r = 0; r < 4; ++r) {
        const int row = mt * 16 + quad * 4 + r;
        sH[row * LDH + n] = f2bf(silu_f(acc[mt][nt][r] + bias));
      }
    }
  }
  __syncthreads();                                  // b3: sH visible

  // ---- GEMM2: K=256; wave covers n-tile `wave`
  f32x4 acc2[4];
#pragma unroll
  for (int mt = 0; mt < 4; ++mt) acc2[mt] = (f32x4){0.f, 0.f, 0.f, 0.f};

  short8 bf2[2];
  bf2[0] = *(const short8*)(w2f + (size_t)(wave * 64 + lane) * 8);

#pragma unroll
  for (int kt = 0; kt < 8; ++kt) {
    if (kt < 7)
      bf2[(kt + 1) & 1] = *(const short8*)(
          w2f + (size_t)(((kt + 1) * 4 + wave) * 64 + lane) * 8);
    short8 af[4];
#pragma unroll
    for (int mt = 0; mt < 4; ++mt)
      af[mt] = *(const short8*)&sH[(mt * 16 + col) * LDH + kt * 32 + quad * 8];
#pragma unroll
    for (int mt = 0; mt < 4; ++mt)
      acc2[mt] = mfma16(af[mt], bf2[kt & 1], acc2[mt]);
  }

  // ---- epilogue: h_new = h + dh -> global, fused per-lane run-reduce of
  // s1/s2 over this lane's 16 ascending rows of the sorted batch.
  {
    const int n = wave * 16 + col;
    const float bias = b2[n];
    float a1 = 0.f, a2 = 0.f;
    int prev = s_b[quad * 4];     // lane's first row (mt=0, r=0)
#pragma unroll
    for (int mt = 0; mt < 4; ++mt) {
#pragma unroll
      for (int r = 0; r < 4; ++r) {
        const int row = mt * 16 + quad * 4 + r;
        const int gi = nb + row;
        const bool valid = gi < N_NODES;
        int g = s_b[row];
        if (g != prev) {
          atomicAdd(&s1[prev * D_MODEL + n], a1);
          atomicAdd(&s2[prev * D_MODEL + n], a2);
          a1 = 0.f; a2 = 0.f; prev = g;
        }
        if (valid) {
          float hv = h[(size_t)gi * D_MODEL + n] + acc2[mt][r] + bias;
          hnew[(size_t)gi * D_MODEL + n] = hv;
          a1 += hv; a2 += hv * hv;
        }
      }
    }
    atomicAdd(&s1[prev * D_MODEL + n], a1);
    atomicAdd(&s2[prev * D_MODEL + n], a2);
  }
}

// ---------------------------------------------------------------------------
// GraphNorm normalize (stats already produced by node_mlp).
// ---------------------------------------------------------------------------
__global__ __launch_bounds__(256)
void gn_norm(float* __restrict__ x, const int* __restrict__ batch,
             const float* __restrict__ s1, const float* __restrict__ s2,
             const float* __restrict__ cnt, const float* __restrict__ alpha,
             const float* __restrict__ weight, const float* __restrict__ bias) {
  int idx = blockIdx.x * 256 + threadIdx.x;
  if (idx >= N_NODES * D_MODEL) return;
  int i = idx >> 6, f = idx & 63;
  int g = batch[i];
  float c = fmaxf(cnt[g], 1.f);
  float m   = s1[g * D_MODEL + f] / c;
  float ex2 = s2[g * D_MODEL + f] / c;
  float a = alpha[f];
  float var = ex2 - 2.f * a * m * m + a * a * m * m;
  float hc = x[idx] - a * m;
  x[idx] = weight[f] * hc * rsqrtf(var + EPS_GN) + bias[f];
}

// ---------------------------------------------------------------------------
extern "C" void kernel_launch(void* const* d_in, const int* in_sizes, int n_in,
                              void* d_out, int out_size, void* d_ws, size_t ws_size,
                              hipStream_t stream) {
  const float* h     = (const float*)d_in[0];
  const float* ea    = (const float*)d_in[1];
  const int*   ei    = (const int*)d_in[2];   // [2][E], row0=src, row1=dst
  const int*   batch = (const int*)d_in[3];
  const float* mw1   = (const float*)d_in[4];
  const float* mb1   = (const float*)d_in[5];
  const float* mw2   = (const float*)d_in[6];
  const float* mb2   = (const float*)d_in[7];
  const float* uw1   = (const float*)d_in[8];
  const float* ub1   = (const float*)d_in[9];
  const float* uw2   = (const float*)d_in[10];
  const float* ub2   = (const float*)d_in[11];
  const float* gw    = (const float*)d_in[12];
  const float* gb    = (const float*)d_in[13];
  const float* ga    = (const float*)d_in[14];

  char* ws = (char*)d_ws;
  float* agg    = (float*)(ws + 0);             // 12,800,000 B
  short* w1f    = (short*)(ws + 12800000);      //     81,920 B
  short* w2f    = (short*)(ws + 12881920);      //     32,768 B
  short* u1f    = (short*)(ws + 12914688);      //     65,536 B
  short* u2f    = (short*)(ws + 12980224);      //     32,768 B
  float* s1     = (float*)(ws + 13012992);      //     16,384 B
  float* s2     = (float*)(ws + 13029376);      //     16,384 B
  float* cnt    = (float*)(ws + 13045760);      //        256 B
  int*   hist   = (int*)  (ws + 13046016);      //    200,704 B (50176 ints)
  int*   offs   = (int*)  (ws + 13246720);      //    200,704 B
  int*   bsums  = (int*)  (ws + 13447424);      //      1,024 B
  int*   bpre   = (int*)  (ws + 13448448);      //      1,024 B
  int*   sorted = (int*)  (ws + 13449472);      //  3,200,000 B
  short* h_bf   = (short*)(ws + 16649472);      //  6,400,000 B -> end 23,049,472

  hipMemsetAsync(agg, 0, 12800000, stream);
  hipMemsetAsync(ws + 13012992, 0, 33024, stream);   // s1, s2, cnt
  hipMemsetAsync(hist, 0, 200704, stream);

  prep_all<<<52 + HBF_BLOCKS, 256, 0, stream>>>(mw1, mw2, uw1, uw2, h,
                                                w1f, w2f, u1f, u2f, h_bf);

  // counting sort of edges by dst
  hist_k  <<<(N_EDGES + 255) / 256, 256, 0, stream>>>(ei, hist);
  scan1   <<<NB_SCAN, 256, 0, stream>>>(hist, offs, bsums);
  scan2   <<<1, 256, 0, stream>>>(bsums, bpre);
  scan3   <<<NB_SCAN, 256, 0, stream>>>(offs, bpre);
  scatter_k<<<(N_EDGES + 255) / 256, 256, 0, stream>>>(ei, offs, sorted);

  edge_mlp<<<N_EDGES / 64, 256, 0, stream>>>(h_bf, ea, ei, sorted,
                                             w1f, mb1, w2f, mb2, agg);

  node_mlp<<<(N_NODES + 63) / 64, 256, 0, stream>>>(h, h_bf, agg,
                                                    u1f, ub1, u2f, ub2,
                                                    batch, (float*)d_out,
                                                    s1, s2, cnt);

  gn_norm<<<(N_NODES * D_MODEL + 255) / 256, 256, 0, stream>>>(
      (float*)d_out, batch, s1, s2, cnt, ga, gw, gb);
}